// Round 11
// baseline (749.157 us; speedup 1.0000x reference)
//
#include <hip/hip_runtime.h>
#include <stdint.h>

// ---------- types ----------
typedef unsigned short u16;
typedef short short8 __attribute__((ext_vector_type(8)));
typedef __bf16 bf16x8 __attribute__((ext_vector_type(8)));
typedef float f32x4 __attribute__((ext_vector_type(4)));

__device__ __forceinline__ u16 f2bf(float f) {
  uint32_t u = __float_as_uint(f);
  u += 0x7fffu + ((u >> 16) & 1u);   // RNE
  return (u16)(u >> 16);
}
__device__ __forceinline__ float bf2f(u16 h) {
  return __uint_as_float(((uint32_t)h) << 16);
}
__device__ __forceinline__ f32x4 mfma16(short8 a, short8 b, f32x4 c) {
  return __builtin_amdgcn_mfma_f32_16x16x32_bf16(
      __builtin_bit_cast(bf16x8, a), __builtin_bit_cast(bf16x8, b), c, 0, 0, 0);
}
__device__ __forceinline__ uint32_t cvtpk_bf16(float lo, float hi) {
  uint32_t r;
  asm("v_cvt_pk_bf16_f32 %0, %1, %2" : "=v"(r) : "v"(lo), "v"(hi));
  return r;
}
// async global->LDS, 16B per lane; LDS dest must be the wave-uniform base.
__device__ __forceinline__ void gld_lds16(const u16* g, u16* lds_base) {
  __builtin_amdgcn_global_load_lds(
      (__attribute__((address_space(1))) void*)g,
      (__attribute__((address_space(3))) void*)lds_base, 16, 0, 0);
}
// raw barrier with compiler-only memory fence (no vmcnt/lgkmcnt drain!)
#define BAR() do { asm volatile("" ::: "memory"); \
                   __builtin_amdgcn_s_barrier(); \
                   asm volatile("" ::: "memory"); } while (0)

// ---------- fp32 -> bf16 convert, all 5 tensors in one launch ----------
__global__ __launch_bounds__(256) void cvt_bf16_5(const float* __restrict__ s0,
                                                  const float* __restrict__ s1,
                                                  const float* __restrict__ s2,
                                                  const float* __restrict__ s3,
                                                  const float* __restrict__ s4,
                                                  u16* __restrict__ dbase) {
  const int gb = blockIdx.x;          // 0..40959
  const int t = gb >> 13;             // tensor id 0..4 (8192 blocks each)
  const float* s = t == 0 ? s0 : t == 1 ? s1 : t == 2 ? s2 : t == 3 ? s3 : s4;
  u16* d = dbase + (size_t)t * 16777216;
  int i = (gb & 8191) * 256 + threadIdx.x;
  const float4* s4p = (const float4*)s;
  float4 a = s4p[2 * i], b = s4p[2 * i + 1];
  uint4 o;
  o.x = (uint32_t)f2bf(a.x) | ((uint32_t)f2bf(a.y) << 16);
  o.y = (uint32_t)f2bf(a.z) | ((uint32_t)f2bf(a.w) << 16);
  o.z = (uint32_t)f2bf(b.x) | ((uint32_t)f2bf(b.y) << 16);
  o.w = (uint32_t)f2bf(b.z) | ((uint32_t)f2bf(b.w) << 16);
  ((uint4*)d)[i] = o;
}

// ---------- NT GEMM, 256x256, 2 phases/K-tile, ds_reads software-pipelined ----------
// R7 structure + one change: each phase's ds_reads are HOISTED into the
// previous phase's post-MFMA region (frag regs dead after their MMs -> zero
// extra VGPR; WAR order preserved). Reads overlap other waves' MFMA tails +
// barrier wait instead of stalling between open-BAR and MFMA (R7: lgkm stall
// on 12-16 just-issued reads was on the critical path -> MfmaUtil 49%).
// Safety: A1[buf] read@t.p0-tail, staged-over only after t.p1 close-BAR;
// {A0,B0,B1}[nbuf] read@t.p1-tail valid since vmcnt(4) before p1's open-BAR
// retired ALL of K-tile t+1; staged-over behind later barriers. Same stage
// schedule / vmcnt invariant / 4 barriers per K-tile as verified R7.
template <int MODE>
__global__ __launch_bounds__(512, 2) void gemm_nt(const u16* __restrict__ A,
                                                  const u16* __restrict__ W,
                                                  void* __restrict__ outp,
                                                  float oscale) {
  constexpr int Kd = 4096;
  __shared__ __align__(16) u16 As[2][2][8192];
  __shared__ __align__(16) u16 Bs[2][2][8192];
  const int tid = threadIdx.x;
  const int wid = tid >> 6, l = tid & 63;
  const int lg = (l >> 4) & 3, lc = l & 15;
  const int wm = wid >> 2, wn = wid & 3;  // 2 x 4 wave grid
  const int bid0 = blockIdx.x;
  const int bid = (bid0 & 7) * 32 + (bid0 >> 3);
  const int m0 = (bid >> 4) * 256, n0 = (bid & 15) * 256;

  const int srow = tid >> 3;                    // 0..63
  const int scol = ((tid & 7) ^ (srow & 7)) * 8;  // swizzled k-slot source, u16
  const int arow = m0 + srow;
  const int browb = n0 + ((srow >> 5) & 1) * 64 + (srow & 31);

#define STAGE_A(BUF, H, T) do { \
    const u16* g0 = A + (size_t)(arow + (H) * 64) * Kd + (T) * 64 + scol; \
    gld_lds16(g0, &As[BUF][H][wid * 512]); \
    gld_lds16(g0 + (size_t)128 * Kd, &As[BUF][H][4096 + wid * 512]); \
  } while (0)
#define STAGE_B(BUF, H, T) do { \
    const u16* g0 = W + (size_t)(browb + (H) * 32) * Kd + (T) * 64 + scol; \
    gld_lds16(g0, &Bs[BUF][H][wid * 512]); \
    gld_lds16(g0 + (size_t)128 * Kd, &Bs[BUF][H][4096 + wid * 512]); \
  } while (0)

  f32x4 acc[8][4];
#pragma unroll
  for (int i = 0; i < 8; ++i)
#pragma unroll
    for (int j = 0; j < 4; ++j) acc[i][j] = (f32x4)0.0f;

  const int axor = (lc & 7);

  short8 af[4][2], b0f[2][2], b1f[2][2];

#define LDA(BUF, MQ) do { \
    const char* Ab_ = (const char*)As[BUF][MQ] + (wm * 64 + lc) * 128; \
    _Pragma("unroll") for (int f = 0; f < 4; ++f) \
      _Pragma("unroll") for (int kk = 0; kk < 2; ++kk) \
        af[f][kk] = *(const short8*)(Ab_ + f * 2048 + (((kk * 4 + lg) ^ axor) << 4)); \
  } while (0)
#define LDB(BUF, DST, NQ) do { \
    const char* Bb_ = (const char*)Bs[BUF][NQ] + (wn * 32 + lc) * 128; \
    _Pragma("unroll") for (int g = 0; g < 2; ++g) \
      _Pragma("unroll") for (int kk = 0; kk < 2; ++kk) \
        DST[g][kk] = *(const short8*)(Bb_ + g * 2048 + (((kk * 4 + lg) ^ axor) << 4)); \
  } while (0)
#define MM(MQ, NQ, BF) do { \
    __builtin_amdgcn_s_setprio(1); \
    _Pragma("unroll") for (int f = 0; f < 4; ++f) \
      _Pragma("unroll") for (int g = 0; g < 2; ++g) \
        _Pragma("unroll") for (int kk = 0; kk < 2; ++kk) \
          acc[(MQ) * 4 + f][(NQ) * 2 + g] = \
              mfma16(af[f][kk], BF[g][kk], acc[(MQ) * 4 + f][(NQ) * 2 + g]); \
    __builtin_amdgcn_s_setprio(0); \
  } while (0)

  // prologue: K0's 4 units + A0(1),B1(1); retire K0; barrier; pre-read t0/p0.
  STAGE_A(0, 0, 0); STAGE_B(0, 1, 0); STAGE_B(0, 0, 0); STAGE_A(0, 1, 0);
  STAGE_A(1, 0, 1); STAGE_B(1, 1, 1);
  asm volatile("s_waitcnt vmcnt(4)" ::: "memory");
  BAR();
  LDA(0, 0); LDB(0, b0f, 0); LDB(0, b1f, 1);

#pragma unroll 1
  for (int t = 0; t < 62; ++t) {
    const int buf = t & 1, nbuf = buf ^ 1;
    // p0: frags pre-read last iter; stage; MFMA; read p1's A1.
    STAGE_B(nbuf, 0, t + 1); STAGE_A(nbuf, 1, t + 1);
    BAR();
    MM(0, 0, b0f); MM(0, 1, b1f);
    LDA(buf, 1);
    BAR();
    // p1: stage; counted vmcnt; MFMA; pre-read next iter's p0 frags.
    STAGE_A(buf, 0, t + 2); STAGE_B(buf, 1, t + 2);
    asm volatile("s_waitcnt vmcnt(4)" ::: "memory");
    BAR();
    MM(1, 1, b1f); MM(1, 0, b0f);
    LDA(nbuf, 0); LDB(nbuf, b0f, 0); LDB(nbuf, b1f, 1);
    BAR();
  }
  {  // t = 62 (buf=0): stage K-tile 63's remaining units; full drain.
    STAGE_B(1, 0, 63); STAGE_A(1, 1, 63);
    BAR();
    MM(0, 0, b0f); MM(0, 1, b1f);
    LDA(0, 1);
    BAR();
    asm volatile("s_waitcnt vmcnt(0)" ::: "memory");
    BAR();
    MM(1, 1, b1f); MM(1, 0, b0f);
    LDA(1, 0); LDB(1, b0f, 0); LDB(1, b1f, 1);
    BAR();
  }
  {  // t = 63 (buf=1): no staging, no barriers needed.
    MM(0, 0, b0f); MM(0, 1, b1f);
    LDA(1, 1);
    MM(1, 1, b1f); MM(1, 0, b0f);
  }
#undef MM
#undef LDB
#undef LDA
#undef STAGE_A
#undef STAGE_B

  const int gr0 = m0 + wm * 128, gc0 = n0 + wn * 64;
#pragma unroll
  for (int mf = 0; mf < 8; ++mf)
#pragma unroll
    for (int nf = 0; nf < 4; ++nf)
#pragma unroll
      for (int r = 0; r < 4; ++r) {
        float v = acc[mf][nf][r] * oscale;
        int gr = gr0 + mf * 16 + lg * 4 + r;  // m index
        int gc = gc0 + nf * 16 + lc;          // n index
        if constexpr (MODE == 0) {
          ((u16*)outp)[((size_t)(((gr >> 11) * 16 + (gc >> 8)) * 2048 +
                                 (gr & 2047))) * 256 + (gc & 255)] = f2bf(v);
        } else if constexpr (MODE == 1) {
          ((u16*)outp)[(size_t)((gr >> 11) * 4096 + gc) * 2048 + (gr & 2047)] =
              f2bf(v);
        } else {
          ((float*)outp)[(size_t)gr * 4096 + gc] = v;
        }
      }
}

// ---------- GPT-J interleaved RoPE on Q,K (first 64 dims/head), in place ----------
__global__ __launch_bounds__(256) void rope_qk(u16* __restrict__ Qb,
                                               u16* __restrict__ Kb,
                                               const int* __restrict__ pos) {
  int idx = blockIdx.x * 256 + threadIdx.x;  // [2][32 bh][2048 s][32 pairs]
  int pair = idx & 31;
  int s = (idx >> 5) & 2047;
  int bh = (idx >> 16) & 31;
  u16* T = (idx >> 21) ? Kb : Qb;
  float p = (float)pos[s];
  float inv = __builtin_amdgcn_exp2f((float)pair * -0.41524101186407984f);
  float ang = p * inv, sn, cs;
  sincosf(ang, &sn, &cs);
  u16* base = T + ((size_t)bh * 2048 + s) * 256 + pair * 2;
  float x1 = bf2f(base[0]), x2 = bf2f(base[1]);
  base[0] = f2bf(x1 * cs - x2 * sn);
  base[1] = f2bf(x2 * cs + x1 * sn);
}

// ---------- causal flash attention (verified R10: 194us, 8-wave blocks) ----------
__global__ __launch_bounds__(512, 2) void flash_attn(const u16* __restrict__ Q,
                                                     const u16* __restrict__ K,
                                                     const u16* __restrict__ Vt,
                                                     u16* __restrict__ ctx) {
  __shared__ u16 Ks[2][32 * 256];
  __shared__ u16 Vs[2][256 * 32];
  __shared__ u16 P[8][16 * 40];

  const int bid = blockIdx.x;            // 0..511
  const int xcd = bid & 7, j = bid >> 3; // j = 0..63 within XCD
  const int hl = (j >> 5) * 2 + ((j >> 4) & 1);  // head 0..3 in XCD
  const int qi = j & 15;
  const int bh = xcd * 4 + hl;
  const int q0 = 1920 - qi * 128;        // 128-row q block, longest first
  const int tid = threadIdx.x;
  const int wid = tid >> 6, l = tid & 63;
  const int lg = l >> 4, lc = l & 15;
  const int qr = q0 + wid * 16;

  const u16* Qh = Q + (size_t)bh * 2048 * 256;
  const u16* Kh = K + (size_t)bh * 2048 * 256;
  const u16* Vh = Vt + (size_t)bh * 256 * 2048;

  // staging: 8 waves x 2 chunks each for K and V (chunk c = wid*2+jj, 1KB)
  int krow[2], kcol[2], vrow[2], vcol[2];
#pragma unroll
  for (int jj = 0; jj < 2; ++jj) {
    int c = wid * 2 + jj;                // 0..15
    krow[jj] = 2 * c + (l >> 5);
    kcol[jj] = ((((l & 31) << 4) ^ ((krow[jj] & 7) << 4)) >> 1);
    vrow[jj] = c * 16 + (l >> 2);
    vcol[jj] = ((((l & 3) << 4) ^ (((vrow[jj] >> 1) & 3) << 4)) >> 1);
  }

  short8 qf[8];
#pragma unroll
  for (int kk = 0; kk < 8; ++kk)
    qf[kk] = *(const short8*)&Qh[(size_t)(qr + lc) * 256 + kk * 32 + lg * 8];

  f32x4 o[16];
#pragma unroll
  for (int nf = 0; nf < 16; ++nf) o[nf] = (f32x4)0.0f;
  float mrow = -1e30f;
  float lrow = 0.0f;  // per-lane partial; reduced once at epilogue

  uint32_t* Pw = (uint32_t*)P[wid];
  const u16* Pm = P[wid];

  const int ntiles = q0 / 32 + 4;

#pragma unroll
  for (int jj = 0; jj < 2; ++jj) {
    gld_lds16(Kh + (size_t)krow[jj] * 256 + kcol[jj], &Ks[0][(wid * 2 + jj) * 512]);
    gld_lds16(Vh + (size_t)vrow[jj] * 2048 + vcol[jj], &Vs[0][(wid * 2 + jj) * 512]);
  }
  __syncthreads();

  for (int t = 0; t < ntiles; ++t) {
    const int buf = t & 1;
    if (t + 1 < ntiles) {
      const int kv1 = (t + 1) << 5;
#pragma unroll
      for (int jj = 0; jj < 2; ++jj) {
        gld_lds16(Kh + (size_t)(kv1 + krow[jj]) * 256 + kcol[jj],
                  &Ks[buf ^ 1][(wid * 2 + jj) * 512]);
        gld_lds16(Vh + (size_t)vrow[jj] * 2048 + kv1 + vcol[jj],
                  &Vs[buf ^ 1][(wid * 2 + jj) * 512]);
      }
    }
    const int kv0 = t << 5;
    const char* KsB = (const char*)Ks[buf];
    const char* VsB = (const char*)Vs[buf];

    // ---- QK^T (swapped): D[kv][q] ----
    f32x4 s0 = (f32x4)0.0f, s1 = (f32x4)0.0f;
    __builtin_amdgcn_s_setprio(1);
#pragma unroll
    for (int kk = 0; kk < 8; ++kk) {
      const int cb = kk * 64 + lg * 16;
      short8 k0 = *(const short8*)(KsB + lc * 512 + (cb ^ ((lc & 7) << 4)));
      short8 k1 = *(const short8*)(KsB + (16 + lc) * 512 + (cb ^ ((lc & 7) << 4)));
      s0 = mfma16(k0, qf[kk], s0);
      s1 = mfma16(k1, qf[kk], s1);
    }
    __builtin_amdgcn_s_setprio(0);

    float sv[8];
#pragma unroll
    for (int r = 0; r < 4; ++r) { sv[r] = s0[r]; sv[4 + r] = s1[r]; }
    if (kv0 + 31 > qr) {
#pragma unroll
      for (int f = 0; f < 2; ++f)
#pragma unroll
        for (int r = 0; r < 4; ++r) {
          int kvg = kv0 + f * 16 + lg * 4 + r;
          if (kvg > qr + lc) sv[f * 4 + r] = -1e30f;
        }
    }
    float m8 = fmaxf(fmaxf(fmaxf(sv[0], sv[1]), fmaxf(sv[2], sv[3])),
                     fmaxf(fmaxf(sv[4], sv[5]), fmaxf(sv[6], sv[7])));
    float pm = fmaxf(m8, __shfl_xor(m8, 16));
    pm = fmaxf(pm, __shfl_xor(pm, 32));
    // defer-max: rescale only when some row's max grew by >8 (P stays <= 2^8)
    if (__ballot(pm > mrow + 8.0f)) {
      float mn = (pm > mrow + 8.0f) ? pm : mrow;
      float alpha = __builtin_amdgcn_exp2f(mrow - mn);
      lrow *= alpha;
      float aa[4];
#pragma unroll
      for (int r = 0; r < 4; ++r) aa[r] = __shfl(alpha, lg * 4 + r);
#pragma unroll
      for (int nf = 0; nf < 16; ++nf) {
        f32x4 t4 = o[nf];
#pragma unroll
        for (int r = 0; r < 4; ++r) t4[r] *= aa[r];
        o[nf] = t4;
      }
      mrow = mn;
    }
    float p[8];
#pragma unroll
    for (int jq = 0; jq < 8; ++jq) p[jq] = __builtin_amdgcn_exp2f(sv[jq] - mrow);
    lrow += ((p[0] + p[1]) + (p[2] + p[3])) + ((p[4] + p[5]) + (p[6] + p[7]));
    asm volatile("" ::: "memory");
    Pw[lc * 20 + lg * 2 + 0] = cvtpk_bf16(p[0], p[1]);
    Pw[lc * 20 + lg * 2 + 1] = cvtpk_bf16(p[2], p[3]);
    Pw[lc * 20 + 8 + lg * 2 + 0] = cvtpk_bf16(p[4], p[5]);
    Pw[lc * 20 + 8 + lg * 2 + 1] = cvtpk_bf16(p[6], p[7]);
    asm volatile("" ::: "memory");
    short8 pf = *(const short8*)&Pm[lc * 40 + lg * 8];
    // ---- PV from LDS V ----
    __builtin_amdgcn_s_setprio(1);
#pragma unroll
    for (int nf = 0; nf < 16; ++nf) {
      const int d = nf * 16 + lc;
      short8 vf = *(const short8*)(VsB + d * 64 + ((lg * 16) ^ (((d >> 1) & 3) << 4)));
      o[nf] = mfma16(pf, vf, o[nf]);
    }
    __builtin_amdgcn_s_setprio(0);
    asm volatile("" ::: "memory");
    __syncthreads();
  }

  float lt = lrow + __shfl_xor(lrow, 16);
  lt += __shfl_xor(lt, 32);
  float il = 1.0f / lt;
  float ia[4];
#pragma unroll
  for (int r = 0; r < 4; ++r) ia[r] = __shfl(il, lg * 4 + r);
  const int crow0 = (bh >> 4) * 2048 + qr;
  const int ccol0 = (bh & 15) * 256;
#pragma unroll
  for (int nf = 0; nf < 16; ++nf)
#pragma unroll
    for (int r = 0; r < 4; ++r)
      ctx[(size_t)(crow0 + lg * 4 + r) * 4096 + ccol0 + nf * 16 + lc] =
          f2bf(o[nf][r] * ia[r]);
}

// ---------- launcher ----------
extern "C" void kernel_launch(void* const* d_in, const int* in_sizes, int n_in,
                              void* d_out, int out_size, void* d_ws, size_t ws_size,
                              hipStream_t stream) {
  const float* hidden = (const float*)d_in[0];
  const float* Wq = (const float*)d_in[1];
  const float* Wk = (const float*)d_in[2];
  const float* Wv = (const float*)d_in[3];
  const float* Wo = (const float*)d_in[4];
  const int* pos = (const int*)d_in[5];

  const size_t NEL = 16777216;  // 4096*4096
  if (ws_size < 6 * NEL * sizeof(u16)) return;  // need 192 MB scratch

  u16* hb = (u16*)d_ws;      // hidden bf16; reused as ctx after QKV GEMMs
  u16* wq = hb + NEL;
  u16* wk = wq + NEL;
  u16* wv = wk + NEL;
  u16* wo = wv + NEL;
  u16* vt = wo + NEL;        // V^T [bh][d][s]
  u16* ctx = hb;
  u16* qb = (u16*)d_out;     // Q,K live in d_out; overwritten by final GEMM
  u16* kb = qb + NEL;

  cvt_bf16_5<<<40960, 256, 0, stream>>>(hidden, Wq, Wk, Wv, Wo, hb);

  // Q pre-scaled by log2(e)/16 so flash softmax runs in exp2 domain.
  gemm_nt<0><<<256, 512, 0, stream>>>(hb, wq, qb, 0.09016844f);
  gemm_nt<0><<<256, 512, 0, stream>>>(hb, wk, kb, 1.0f);
  gemm_nt<1><<<256, 512, 0, stream>>>(hb, wv, vt, 1.0f);

  rope_qk<<<16384, 256, 0, stream>>>(qb, kb, pos);

  flash_attn<<<512, 512, 0, stream>>>(qb, kb, vt, ctx);

  gemm_nt<2><<<256, 512, 0, stream>>>(ctx, wo, d_out, 1.0f);
}

// Round 12
// 717.691 us; speedup vs baseline: 1.0438x; 1.0438x over previous
//
#include <hip/hip_runtime.h>
#include <stdint.h>

// ---------- types ----------
typedef unsigned short u16;
typedef short short8 __attribute__((ext_vector_type(8)));
typedef __bf16 bf16x8 __attribute__((ext_vector_type(8)));
typedef float f32x4 __attribute__((ext_vector_type(4)));

__device__ __forceinline__ u16 f2bf(float f) {
  uint32_t u = __float_as_uint(f);
  u += 0x7fffu + ((u >> 16) & 1u);   // RNE
  return (u16)(u >> 16);
}
__device__ __forceinline__ float bf2f(u16 h) {
  return __uint_as_float(((uint32_t)h) << 16);
}
__device__ __forceinline__ f32x4 mfma16(short8 a, short8 b, f32x4 c) {
  return __builtin_amdgcn_mfma_f32_16x16x32_bf16(
      __builtin_bit_cast(bf16x8, a), __builtin_bit_cast(bf16x8, b), c, 0, 0, 0);
}
__device__ __forceinline__ uint32_t cvtpk_bf16(float lo, float hi) {
  uint32_t r;
  asm("v_cvt_pk_bf16_f32 %0, %1, %2" : "=v"(r) : "v"(lo), "v"(hi));
  return r;
}
// async global->LDS, 16B per lane; LDS dest must be the wave-uniform base.
__device__ __forceinline__ void gld_lds16(const u16* g, u16* lds_base) {
  __builtin_amdgcn_global_load_lds(
      (__attribute__((address_space(1))) void*)g,
      (__attribute__((address_space(3))) void*)lds_base, 16, 0, 0);
}
// raw barrier with compiler-only memory fence (no vmcnt/lgkmcnt drain!)
#define BAR() do { asm volatile("" ::: "memory"); \
                   __builtin_amdgcn_s_barrier(); \
                   asm volatile("" ::: "memory"); } while (0)

// ---------- fp32 -> bf16 convert, all 5 tensors in one launch ----------
__global__ __launch_bounds__(256) void cvt_bf16_5(const float* __restrict__ s0,
                                                  const float* __restrict__ s1,
                                                  const float* __restrict__ s2,
                                                  const float* __restrict__ s3,
                                                  const float* __restrict__ s4,
                                                  u16* __restrict__ dbase) {
  const int gb = blockIdx.x;          // 0..40959
  const int t = gb >> 13;             // tensor id 0..4 (8192 blocks each)
  const float* s = t == 0 ? s0 : t == 1 ? s1 : t == 2 ? s2 : t == 3 ? s3 : s4;
  u16* d = dbase + (size_t)t * 16777216;
  int i = (gb & 8191) * 256 + threadIdx.x;
  const float4* s4p = (const float4*)s;
  float4 a = s4p[2 * i], b = s4p[2 * i + 1];
  uint4 o;
  o.x = (uint32_t)f2bf(a.x) | ((uint32_t)f2bf(a.y) << 16);
  o.y = (uint32_t)f2bf(a.z) | ((uint32_t)f2bf(a.w) << 16);
  o.z = (uint32_t)f2bf(b.x) | ((uint32_t)f2bf(b.y) << 16);
  o.w = (uint32_t)f2bf(b.z) | ((uint32_t)f2bf(b.w) << 16);
  ((uint4*)d)[i] = o;
}

// ---------- NT GEMM, 256x256, 2 merged phases/K-tile (verified R7/R10, ~1215 TF) ----------
// R11's ds_read hoist REGRESSED (reads pre-barrier already overlap via the
// barrier-wait window; hoisting extended frag live ranges). This is the
// verified R7 schedule: p0 reads A0+B0+B1 pre-BAR, p1 reads A1 pre-BAR;
// stage B0,A1(t+1)->nbuf @p0, A0,B1(t+2)->buf @p1; vmcnt(4) before p1's
// open-BAR retires all of K-tile t+1, leaving 2 units in flight.
template <int MODE>
__global__ __launch_bounds__(512, 2) void gemm_nt(const u16* __restrict__ A,
                                                  const u16* __restrict__ W,
                                                  void* __restrict__ outp,
                                                  float oscale) {
  constexpr int Kd = 4096;
  __shared__ __align__(16) u16 As[2][2][8192];
  __shared__ __align__(16) u16 Bs[2][2][8192];
  const int tid = threadIdx.x;
  const int wid = tid >> 6, l = tid & 63;
  const int lg = (l >> 4) & 3, lc = l & 15;
  const int wm = wid >> 2, wn = wid & 3;  // 2 x 4 wave grid
  const int bid0 = blockIdx.x;
  const int bid = (bid0 & 7) * 32 + (bid0 >> 3);
  const int m0 = (bid >> 4) * 256, n0 = (bid & 15) * 256;

  const int srow = tid >> 3;                    // 0..63
  const int scol = ((tid & 7) ^ (srow & 7)) * 8;  // swizzled k-slot source, u16
  const int arow = m0 + srow;
  const int browb = n0 + ((srow >> 5) & 1) * 64 + (srow & 31);

#define STAGE_A(BUF, H, T) do { \
    const u16* g0 = A + (size_t)(arow + (H) * 64) * Kd + (T) * 64 + scol; \
    gld_lds16(g0, &As[BUF][H][wid * 512]); \
    gld_lds16(g0 + (size_t)128 * Kd, &As[BUF][H][4096 + wid * 512]); \
  } while (0)
#define STAGE_B(BUF, H, T) do { \
    const u16* g0 = W + (size_t)(browb + (H) * 32) * Kd + (T) * 64 + scol; \
    gld_lds16(g0, &Bs[BUF][H][wid * 512]); \
    gld_lds16(g0 + (size_t)128 * Kd, &Bs[BUF][H][4096 + wid * 512]); \
  } while (0)

  f32x4 acc[8][4];
#pragma unroll
  for (int i = 0; i < 8; ++i)
#pragma unroll
    for (int j = 0; j < 4; ++j) acc[i][j] = (f32x4)0.0f;

  const int axor = (lc & 7);

  short8 af[4][2], b0f[2][2], b1f[2][2];

#define LDA(MQ) do { \
    const char* Ab_ = (const char*)As[buf][MQ] + (wm * 64 + lc) * 128; \
    _Pragma("unroll") for (int f = 0; f < 4; ++f) \
      _Pragma("unroll") for (int kk = 0; kk < 2; ++kk) \
        af[f][kk] = *(const short8*)(Ab_ + f * 2048 + (((kk * 4 + lg) ^ axor) << 4)); \
  } while (0)
#define LDB(DST, NQ) do { \
    const char* Bb_ = (const char*)Bs[buf][NQ] + (wn * 32 + lc) * 128; \
    _Pragma("unroll") for (int g = 0; g < 2; ++g) \
      _Pragma("unroll") for (int kk = 0; kk < 2; ++kk) \
        DST[g][kk] = *(const short8*)(Bb_ + g * 2048 + (((kk * 4 + lg) ^ axor) << 4)); \
  } while (0)
#define MM(MQ, NQ, BF) do { \
    __builtin_amdgcn_s_setprio(1); \
    _Pragma("unroll") for (int f = 0; f < 4; ++f) \
      _Pragma("unroll") for (int g = 0; g < 2; ++g) \
        _Pragma("unroll") for (int kk = 0; kk < 2; ++kk) \
          acc[(MQ) * 4 + f][(NQ) * 2 + g] = \
              mfma16(af[f][kk], BF[g][kk], acc[(MQ) * 4 + f][(NQ) * 2 + g]); \
    __builtin_amdgcn_s_setprio(0); \
  } while (0)

  // prologue: K0's 4 units + A0(1),B1(1); retire K0; barrier.
  STAGE_A(0, 0, 0); STAGE_B(0, 1, 0); STAGE_B(0, 0, 0); STAGE_A(0, 1, 0);
  STAGE_A(1, 0, 1); STAGE_B(1, 1, 1);
  asm volatile("s_waitcnt vmcnt(4)" ::: "memory");
  BAR();

#pragma unroll 1
  for (int t = 0; t < 62; ++t) {
    const int buf = t & 1, nbuf = buf ^ 1;
    LDA(0); LDB(b0f, 0); LDB(b1f, 1);
    STAGE_B(nbuf, 0, t + 1); STAGE_A(nbuf, 1, t + 1);
    BAR(); MM(0, 0, b0f); MM(0, 1, b1f); BAR();
    LDA(1);
    STAGE_A(buf, 0, t + 2); STAGE_B(buf, 1, t + 2);
    asm volatile("s_waitcnt vmcnt(4)" ::: "memory");
    BAR(); MM(1, 1, b1f); MM(1, 0, b0f); BAR();
  }
  {  // t = 62: stage only K-tile 63's remaining units; full drain.
    const int buf = 0, nbuf = 1;
    LDA(0); LDB(b0f, 0); LDB(b1f, 1);
    STAGE_B(nbuf, 0, 63); STAGE_A(nbuf, 1, 63);
    BAR(); MM(0, 0, b0f); MM(0, 1, b1f); BAR();
    LDA(1);
    asm volatile("s_waitcnt vmcnt(0)" ::: "memory");
    BAR(); MM(1, 1, b1f); MM(1, 0, b0f); BAR();
  }
  {  // t = 63: no staging.
    const int buf = 1;
    LDA(0); LDB(b0f, 0); LDB(b1f, 1);
    BAR(); MM(0, 0, b0f); MM(0, 1, b1f); BAR();
    LDA(1);
    BAR(); MM(1, 1, b1f); MM(1, 0, b0f); BAR();
  }
#undef MM
#undef LDB
#undef LDA
#undef STAGE_A
#undef STAGE_B

  const int gr0 = m0 + wm * 128, gc0 = n0 + wn * 64;
#pragma unroll
  for (int mf = 0; mf < 8; ++mf)
#pragma unroll
    for (int nf = 0; nf < 4; ++nf)
#pragma unroll
      for (int r = 0; r < 4; ++r) {
        float v = acc[mf][nf][r] * oscale;
        int gr = gr0 + mf * 16 + lg * 4 + r;  // m index
        int gc = gc0 + nf * 16 + lc;          // n index
        if constexpr (MODE == 0) {
          ((u16*)outp)[((size_t)(((gr >> 11) * 16 + (gc >> 8)) * 2048 +
                                 (gr & 2047))) * 256 + (gc & 255)] = f2bf(v);
        } else if constexpr (MODE == 1) {
          ((u16*)outp)[(size_t)((gr >> 11) * 4096 + gc) * 2048 + (gr & 2047)] =
              f2bf(v);
        } else {
          ((float*)outp)[(size_t)gr * 4096 + gc] = v;
        }
      }
}

// ---------- GPT-J interleaved RoPE on Q,K (first 64 dims/head), in place ----------
__global__ __launch_bounds__(256) void rope_qk(u16* __restrict__ Qb,
                                               u16* __restrict__ Kb,
                                               const int* __restrict__ pos) {
  int idx = blockIdx.x * 256 + threadIdx.x;  // [2][32 bh][2048 s][32 pairs]
  int pair = idx & 31;
  int s = (idx >> 5) & 2047;
  int bh = (idx >> 16) & 31;
  u16* T = (idx >> 21) ? Kb : Qb;
  float p = (float)pos[s];
  float inv = __builtin_amdgcn_exp2f((float)pair * -0.41524101186407984f);
  float ang = p * inv, sn, cs;
  sincosf(ang, &sn, &cs);
  u16* base = T + ((size_t)bh * 2048 + s) * 256 + pair * 2;
  float x1 = bf2f(base[0]), x2 = bf2f(base[1]);
  base[0] = f2bf(x1 * cs - x2 * sn);
  base[1] = f2bf(x2 * cs + x1 * sn);
}

// ---------- causal flash attention (verified R10: 194us, 8-wave blocks) ----------
__global__ __launch_bounds__(512, 2) void flash_attn(const u16* __restrict__ Q,
                                                     const u16* __restrict__ K,
                                                     const u16* __restrict__ Vt,
                                                     u16* __restrict__ ctx) {
  __shared__ u16 Ks[2][32 * 256];
  __shared__ u16 Vs[2][256 * 32];
  __shared__ u16 P[8][16 * 40];

  const int bid = blockIdx.x;            // 0..511
  const int xcd = bid & 7, j = bid >> 3; // j = 0..63 within XCD
  const int hl = (j >> 5) * 2 + ((j >> 4) & 1);  // head 0..3 in XCD
  const int qi = j & 15;
  const int bh = xcd * 4 + hl;
  const int q0 = 1920 - qi * 128;        // 128-row q block, longest first
  const int tid = threadIdx.x;
  const int wid = tid >> 6, l = tid & 63;
  const int lg = l >> 4, lc = l & 15;
  const int qr = q0 + wid * 16;

  const u16* Qh = Q + (size_t)bh * 2048 * 256;
  const u16* Kh = K + (size_t)bh * 2048 * 256;
  const u16* Vh = Vt + (size_t)bh * 256 * 2048;

  // staging: 8 waves x 2 chunks each for K and V (chunk c = wid*2+jj, 1KB)
  int krow[2], kcol[2], vrow[2], vcol[2];
#pragma unroll
  for (int jj = 0; jj < 2; ++jj) {
    int c = wid * 2 + jj;                // 0..15
    krow[jj] = 2 * c + (l >> 5);
    kcol[jj] = ((((l & 31) << 4) ^ ((krow[jj] & 7) << 4)) >> 1);
    vrow[jj] = c * 16 + (l >> 2);
    vcol[jj] = ((((l & 3) << 4) ^ (((vrow[jj] >> 1) & 3) << 4)) >> 1);
  }

  short8 qf[8];
#pragma unroll
  for (int kk = 0; kk < 8; ++kk)
    qf[kk] = *(const short8*)&Qh[(size_t)(qr + lc) * 256 + kk * 32 + lg * 8];

  f32x4 o[16];
#pragma unroll
  for (int nf = 0; nf < 16; ++nf) o[nf] = (f32x4)0.0f;
  float mrow = -1e30f;
  float lrow = 0.0f;  // per-lane partial; reduced once at epilogue

  uint32_t* Pw = (uint32_t*)P[wid];
  const u16* Pm = P[wid];

  const int ntiles = q0 / 32 + 4;

#pragma unroll
  for (int jj = 0; jj < 2; ++jj) {
    gld_lds16(Kh + (size_t)krow[jj] * 256 + kcol[jj], &Ks[0][(wid * 2 + jj) * 512]);
    gld_lds16(Vh + (size_t)vrow[jj] * 2048 + vcol[jj], &Vs[0][(wid * 2 + jj) * 512]);
  }
  __syncthreads();

  for (int t = 0; t < ntiles; ++t) {
    const int buf = t & 1;
    if (t + 1 < ntiles) {
      const int kv1 = (t + 1) << 5;
#pragma unroll
      for (int jj = 0; jj < 2; ++jj) {
        gld_lds16(Kh + (size_t)(kv1 + krow[jj]) * 256 + kcol[jj],
                  &Ks[buf ^ 1][(wid * 2 + jj) * 512]);
        gld_lds16(Vh + (size_t)vrow[jj] * 2048 + kv1 + vcol[jj],
                  &Vs[buf ^ 1][(wid * 2 + jj) * 512]);
      }
    }
    const int kv0 = t << 5;
    const char* KsB = (const char*)Ks[buf];
    const char* VsB = (const char*)Vs[buf];

    // ---- QK^T (swapped): D[kv][q] ----
    f32x4 s0 = (f32x4)0.0f, s1 = (f32x4)0.0f;
    __builtin_amdgcn_s_setprio(1);
#pragma unroll
    for (int kk = 0; kk < 8; ++kk) {
      const int cb = kk * 64 + lg * 16;
      short8 k0 = *(const short8*)(KsB + lc * 512 + (cb ^ ((lc & 7) << 4)));
      short8 k1 = *(const short8*)(KsB + (16 + lc) * 512 + (cb ^ ((lc & 7) << 4)));
      s0 = mfma16(k0, qf[kk], s0);
      s1 = mfma16(k1, qf[kk], s1);
    }
    __builtin_amdgcn_s_setprio(0);

    float sv[8];
#pragma unroll
    for (int r = 0; r < 4; ++r) { sv[r] = s0[r]; sv[4 + r] = s1[r]; }
    if (kv0 + 31 > qr) {
#pragma unroll
      for (int f = 0; f < 2; ++f)
#pragma unroll
        for (int r = 0; r < 4; ++r) {
          int kvg = kv0 + f * 16 + lg * 4 + r;
          if (kvg > qr + lc) sv[f * 4 + r] = -1e30f;
        }
    }
    float m8 = fmaxf(fmaxf(fmaxf(sv[0], sv[1]), fmaxf(sv[2], sv[3])),
                     fmaxf(fmaxf(sv[4], sv[5]), fmaxf(sv[6], sv[7])));
    float pm = fmaxf(m8, __shfl_xor(m8, 16));
    pm = fmaxf(pm, __shfl_xor(pm, 32));
    // defer-max: rescale only when some row's max grew by >8 (P stays <= 2^8)
    if (__ballot(pm > mrow + 8.0f)) {
      float mn = (pm > mrow + 8.0f) ? pm : mrow;
      float alpha = __builtin_amdgcn_exp2f(mrow - mn);
      lrow *= alpha;
      float aa[4];
#pragma unroll
      for (int r = 0; r < 4; ++r) aa[r] = __shfl(alpha, lg * 4 + r);
#pragma unroll
      for (int nf = 0; nf < 16; ++nf) {
        f32x4 t4 = o[nf];
#pragma unroll
        for (int r = 0; r < 4; ++r) t4[r] *= aa[r];
        o[nf] = t4;
      }
      mrow = mn;
    }
    float p[8];
#pragma unroll
    for (int jq = 0; jq < 8; ++jq) p[jq] = __builtin_amdgcn_exp2f(sv[jq] - mrow);
    lrow += ((p[0] + p[1]) + (p[2] + p[3])) + ((p[4] + p[5]) + (p[6] + p[7]));
    asm volatile("" ::: "memory");
    Pw[lc * 20 + lg * 2 + 0] = cvtpk_bf16(p[0], p[1]);
    Pw[lc * 20 + lg * 2 + 1] = cvtpk_bf16(p[2], p[3]);
    Pw[lc * 20 + 8 + lg * 2 + 0] = cvtpk_bf16(p[4], p[5]);
    Pw[lc * 20 + 8 + lg * 2 + 1] = cvtpk_bf16(p[6], p[7]);
    asm volatile("" ::: "memory");
    short8 pf = *(const short8*)&Pm[lc * 40 + lg * 8];
    // ---- PV from LDS V ----
    __builtin_amdgcn_s_setprio(1);
#pragma unroll
    for (int nf = 0; nf < 16; ++nf) {
      const int d = nf * 16 + lc;
      short8 vf = *(const short8*)(VsB + d * 64 + ((lg * 16) ^ (((d >> 1) & 3) << 4)));
      o[nf] = mfma16(pf, vf, o[nf]);
    }
    __builtin_amdgcn_s_setprio(0);
    asm volatile("" ::: "memory");
    __syncthreads();
  }

  float lt = lrow + __shfl_xor(lrow, 16);
  lt += __shfl_xor(lt, 32);
  float il = 1.0f / lt;
  float ia[4];
#pragma unroll
  for (int r = 0; r < 4; ++r) ia[r] = __shfl(il, lg * 4 + r);
  const int crow0 = (bh >> 4) * 2048 + qr;
  const int ccol0 = (bh & 15) * 256;
#pragma unroll
  for (int nf = 0; nf < 16; ++nf)
#pragma unroll
    for (int r = 0; r < 4; ++r)
      ctx[(size_t)(crow0 + lg * 4 + r) * 4096 + ccol0 + nf * 16 + lc] =
          f2bf(o[nf][r] * ia[r]);
}

// ---------- launcher ----------
extern "C" void kernel_launch(void* const* d_in, const int* in_sizes, int n_in,
                              void* d_out, int out_size, void* d_ws, size_t ws_size,
                              hipStream_t stream) {
  const float* hidden = (const float*)d_in[0];
  const float* Wq = (const float*)d_in[1];
  const float* Wk = (const float*)d_in[2];
  const float* Wv = (const float*)d_in[3];
  const float* Wo = (const float*)d_in[4];
  const int* pos = (const int*)d_in[5];

  const size_t NEL = 16777216;  // 4096*4096
  if (ws_size < 6 * NEL * sizeof(u16)) return;  // need 192 MB scratch

  u16* hb = (u16*)d_ws;      // hidden bf16; reused as ctx after QKV GEMMs
  u16* wq = hb + NEL;
  u16* wk = wq + NEL;
  u16* wv = wk + NEL;
  u16* wo = wv + NEL;
  u16* vt = wo + NEL;        // V^T [bh][d][s]
  u16* ctx = hb;
  u16* qb = (u16*)d_out;     // Q,K live in d_out; overwritten by final GEMM
  u16* kb = qb + NEL;

  cvt_bf16_5<<<40960, 256, 0, stream>>>(hidden, Wq, Wk, Wv, Wo, hb);

  // Q pre-scaled by log2(e)/16 so flash softmax runs in exp2 domain.
  gemm_nt<0><<<256, 512, 0, stream>>>(hb, wq, qb, 0.09016844f);
  gemm_nt<0><<<256, 512, 0, stream>>>(hb, wk, kb, 1.0f);
  gemm_nt<1><<<256, 512, 0, stream>>>(hb, wv, vt, 1.0f);

  rope_qk<<<16384, 256, 0, stream>>>(qb, kb, pos);

  flash_attn<<<512, 512, 0, stream>>>(qb, kb, vt, ctx);

  gemm_nt<2><<<256, 512, 0, stream>>>(ctx, wo, d_out, 1.0f);
}

// Round 13
// 713.174 us; speedup vs baseline: 1.0505x; 1.0063x over previous
//
#include <hip/hip_runtime.h>
#include <stdint.h>

// ---------- types ----------
typedef unsigned short u16;
typedef short short8 __attribute__((ext_vector_type(8)));
typedef __bf16 bf16x8 __attribute__((ext_vector_type(8)));
typedef float f32x4 __attribute__((ext_vector_type(4)));

__device__ __forceinline__ u16 f2bf(float f) {
  uint32_t u = __float_as_uint(f);
  u += 0x7fffu + ((u >> 16) & 1u);   // RNE
  return (u16)(u >> 16);
}
__device__ __forceinline__ float bf2f(u16 h) {
  return __uint_as_float(((uint32_t)h) << 16);
}
__device__ __forceinline__ f32x4 mfma16(short8 a, short8 b, f32x4 c) {
  return __builtin_amdgcn_mfma_f32_16x16x32_bf16(
      __builtin_bit_cast(bf16x8, a), __builtin_bit_cast(bf16x8, b), c, 0, 0, 0);
}
__device__ __forceinline__ uint32_t cvtpk_bf16(float lo, float hi) {
  uint32_t r;
  asm("v_cvt_pk_bf16_f32 %0, %1, %2" : "=v"(r) : "v"(lo), "v"(hi));
  return r;
}
// async global->LDS, 16B per lane; LDS dest must be the wave-uniform base.
__device__ __forceinline__ void gld_lds16(const u16* g, u16* lds_base) {
  __builtin_amdgcn_global_load_lds(
      (__attribute__((address_space(1))) void*)g,
      (__attribute__((address_space(3))) void*)lds_base, 16, 0, 0);
}
// raw barrier with compiler-only memory fence (no vmcnt/lgkmcnt drain!)
#define BAR() do { asm volatile("" ::: "memory"); \
                   __builtin_amdgcn_s_barrier(); \
                   asm volatile("" ::: "memory"); } while (0)

// ---------- fp32 -> bf16 convert, all 5 tensors in one launch ----------
__global__ __launch_bounds__(256) void cvt_bf16_5(const float* __restrict__ s0,
                                                  const float* __restrict__ s1,
                                                  const float* __restrict__ s2,
                                                  const float* __restrict__ s3,
                                                  const float* __restrict__ s4,
                                                  u16* __restrict__ dbase) {
  const int gb = blockIdx.x;          // 0..40959
  const int t = gb >> 13;             // tensor id 0..4 (8192 blocks each)
  const float* s = t == 0 ? s0 : t == 1 ? s1 : t == 2 ? s2 : t == 3 ? s3 : s4;
  u16* d = dbase + (size_t)t * 16777216;
  int i = (gb & 8191) * 256 + threadIdx.x;
  const float4* s4p = (const float4*)s;
  float4 a = s4p[2 * i], b = s4p[2 * i + 1];
  uint4 o;
  o.x = (uint32_t)f2bf(a.x) | ((uint32_t)f2bf(a.y) << 16);
  o.y = (uint32_t)f2bf(a.z) | ((uint32_t)f2bf(a.w) << 16);
  o.z = (uint32_t)f2bf(b.x) | ((uint32_t)f2bf(b.y) << 16);
  o.w = (uint32_t)f2bf(b.z) | ((uint32_t)f2bf(b.w) << 16);
  ((uint4*)d)[i] = o;
}

// ---------- NT GEMM, 256x256, 2 merged phases/K-tile (verified R7/R10, ~1215 TF) ----------
template <int MODE>
__global__ __launch_bounds__(512, 2) void gemm_nt(const u16* __restrict__ A,
                                                  const u16* __restrict__ W,
                                                  void* __restrict__ outp,
                                                  float oscale) {
  constexpr int Kd = 4096;
  __shared__ __align__(16) u16 As[2][2][8192];
  __shared__ __align__(16) u16 Bs[2][2][8192];
  const int tid = threadIdx.x;
  const int wid = tid >> 6, l = tid & 63;
  const int lg = (l >> 4) & 3, lc = l & 15;
  const int wm = wid >> 2, wn = wid & 3;  // 2 x 4 wave grid
  const int bid0 = blockIdx.x;
  const int bid = (bid0 & 7) * 32 + (bid0 >> 3);
  const int m0 = (bid >> 4) * 256, n0 = (bid & 15) * 256;

  const int srow = tid >> 3;                    // 0..63
  const int scol = ((tid & 7) ^ (srow & 7)) * 8;  // swizzled k-slot source, u16
  const int arow = m0 + srow;
  const int browb = n0 + ((srow >> 5) & 1) * 64 + (srow & 31);

#define STAGE_A(BUF, H, T) do { \
    const u16* g0 = A + (size_t)(arow + (H) * 64) * Kd + (T) * 64 + scol; \
    gld_lds16(g0, &As[BUF][H][wid * 512]); \
    gld_lds16(g0 + (size_t)128 * Kd, &As[BUF][H][4096 + wid * 512]); \
  } while (0)
#define STAGE_B(BUF, H, T) do { \
    const u16* g0 = W + (size_t)(browb + (H) * 32) * Kd + (T) * 64 + scol; \
    gld_lds16(g0, &Bs[BUF][H][wid * 512]); \
    gld_lds16(g0 + (size_t)128 * Kd, &Bs[BUF][H][4096 + wid * 512]); \
  } while (0)

  f32x4 acc[8][4];
#pragma unroll
  for (int i = 0; i < 8; ++i)
#pragma unroll
    for (int j = 0; j < 4; ++j) acc[i][j] = (f32x4)0.0f;

  const int axor = (lc & 7);

  short8 af[4][2], b0f[2][2], b1f[2][2];

#define LDA(MQ) do { \
    const char* Ab_ = (const char*)As[buf][MQ] + (wm * 64 + lc) * 128; \
    _Pragma("unroll") for (int f = 0; f < 4; ++f) \
      _Pragma("unroll") for (int kk = 0; kk < 2; ++kk) \
        af[f][kk] = *(const short8*)(Ab_ + f * 2048 + (((kk * 4 + lg) ^ axor) << 4)); \
  } while (0)
#define LDB(DST, NQ) do { \
    const char* Bb_ = (const char*)Bs[buf][NQ] + (wn * 32 + lc) * 128; \
    _Pragma("unroll") for (int g = 0; g < 2; ++g) \
      _Pragma("unroll") for (int kk = 0; kk < 2; ++kk) \
        DST[g][kk] = *(const short8*)(Bb_ + g * 2048 + (((kk * 4 + lg) ^ axor) << 4)); \
  } while (0)
#define MM(MQ, NQ, BF) do { \
    __builtin_amdgcn_s_setprio(1); \
    _Pragma("unroll") for (int f = 0; f < 4; ++f) \
      _Pragma("unroll") for (int g = 0; g < 2; ++g) \
        _Pragma("unroll") for (int kk = 0; kk < 2; ++kk) \
          acc[(MQ) * 4 + f][(NQ) * 2 + g] = \
              mfma16(af[f][kk], BF[g][kk], acc[(MQ) * 4 + f][(NQ) * 2 + g]); \
    __builtin_amdgcn_s_setprio(0); \
  } while (0)

  // prologue: K0's 4 units + A0(1),B1(1); retire K0; barrier.
  STAGE_A(0, 0, 0); STAGE_B(0, 1, 0); STAGE_B(0, 0, 0); STAGE_A(0, 1, 0);
  STAGE_A(1, 0, 1); STAGE_B(1, 1, 1);
  asm volatile("s_waitcnt vmcnt(4)" ::: "memory");
  BAR();

#pragma unroll 1
  for (int t = 0; t < 62; ++t) {
    const int buf = t & 1, nbuf = buf ^ 1;
    LDA(0); LDB(b0f, 0); LDB(b1f, 1);
    STAGE_B(nbuf, 0, t + 1); STAGE_A(nbuf, 1, t + 1);
    BAR(); MM(0, 0, b0f); MM(0, 1, b1f); BAR();
    LDA(1);
    STAGE_A(buf, 0, t + 2); STAGE_B(buf, 1, t + 2);
    asm volatile("s_waitcnt vmcnt(4)" ::: "memory");
    BAR(); MM(1, 1, b1f); MM(1, 0, b0f); BAR();
  }
  {  // t = 62: stage only K-tile 63's remaining units; full drain.
    const int buf = 0, nbuf = 1;
    LDA(0); LDB(b0f, 0); LDB(b1f, 1);
    STAGE_B(nbuf, 0, 63); STAGE_A(nbuf, 1, 63);
    BAR(); MM(0, 0, b0f); MM(0, 1, b1f); BAR();
    LDA(1);
    asm volatile("s_waitcnt vmcnt(0)" ::: "memory");
    BAR(); MM(1, 1, b1f); MM(1, 0, b0f); BAR();
  }
  {  // t = 63: no staging.
    const int buf = 1;
    LDA(0); LDB(b0f, 0); LDB(b1f, 1);
    BAR(); MM(0, 0, b0f); MM(0, 1, b1f); BAR();
    LDA(1);
    BAR(); MM(1, 1, b1f); MM(1, 0, b0f); BAR();
  }
#undef MM
#undef LDB
#undef LDA
#undef STAGE_A
#undef STAGE_B

  const int gr0 = m0 + wm * 128, gc0 = n0 + wn * 64;
#pragma unroll
  for (int mf = 0; mf < 8; ++mf)
#pragma unroll
    for (int nf = 0; nf < 4; ++nf)
#pragma unroll
      for (int r = 0; r < 4; ++r) {
        float v = acc[mf][nf][r] * oscale;
        int gr = gr0 + mf * 16 + lg * 4 + r;  // m index
        int gc = gc0 + nf * 16 + lc;          // n index
        if constexpr (MODE == 0) {
          ((u16*)outp)[((size_t)(((gr >> 11) * 16 + (gc >> 8)) * 2048 +
                                 (gr & 2047))) * 256 + (gc & 255)] = f2bf(v);
        } else if constexpr (MODE == 1) {
          ((u16*)outp)[(size_t)((gr >> 11) * 4096 + gc) * 2048 + (gr & 2047)] =
              f2bf(v);
        } else {
          ((float*)outp)[(size_t)gr * 4096 + gc] = v;
        }
      }
}

// ---------- GPT-J interleaved RoPE on Q,K (first 64 dims/head), in place ----------
__global__ __launch_bounds__(256) void rope_qk(u16* __restrict__ Qb,
                                               u16* __restrict__ Kb,
                                               const int* __restrict__ pos) {
  int idx = blockIdx.x * 256 + threadIdx.x;  // [2][32 bh][2048 s][32 pairs]
  int pair = idx & 31;
  int s = (idx >> 5) & 2047;
  int bh = (idx >> 16) & 31;
  u16* T = (idx >> 21) ? Kb : Qb;
  float p = (float)pos[s];
  float inv = __builtin_amdgcn_exp2f((float)pair * -0.41524101186407984f);
  float ang = p * inv, sn, cs;
  sincosf(ang, &sn, &cs);
  u16* base = T + ((size_t)bh * 2048 + s) * 256 + pair * 2;
  float x1 = bf2f(base[0]), x2 = bf2f(base[1]);
  base[0] = f2bf(x1 * cs - x2 * sn);
  base[1] = f2bf(x2 * cs + x1 * sn);
}

// ---------- causal flash attention v7: cross-CU work balancing ----------
// R10 structure (8-wave/128-row blocks, 16 waves/CU). ONE change: the second
// half of each XCD's blocks runs qi MIRRORED (15-r) so each CU's two resident
// blocks have trip counts (64-4q) and (4+4q) -> SUM = 68 constant across ALL
// CUs. R10-R12 paired equal-length blocks (both qi=c&15): per-CU work ranged
// 8..128 slots vs mean 68 -> makespan set by qi=0 CUs, avg occupancy 14%.
// Long blocks still dispatch first (greedy LPT); coverage stays bijective.
__global__ __launch_bounds__(512, 2) void flash_attn(const u16* __restrict__ Q,
                                                     const u16* __restrict__ K,
                                                     const u16* __restrict__ Vt,
                                                     u16* __restrict__ ctx) {
  __shared__ u16 Ks[2][32 * 256];
  __shared__ u16 Vs[2][256 * 32];
  __shared__ u16 P[8][16 * 40];

  const int bid = blockIdx.x;            // 0..511
  const int xcd = bid & 7, j = bid >> 3; // j = 0..63 within XCD
  const int hl = (j >> 5) * 2 + ((j >> 4) & 1);  // head 0..3 in XCD
  const int r_ = j & 15;
  const int qi = (j < 32) ? r_ : (15 - r_);      // mirrored second half
  const int bh = xcd * 4 + hl;
  const int q0 = 1920 - qi * 128;        // 128-row q block
  const int tid = threadIdx.x;
  const int wid = tid >> 6, l = tid & 63;
  const int lg = l >> 4, lc = l & 15;
  const int qr = q0 + wid * 16;

  const u16* Qh = Q + (size_t)bh * 2048 * 256;
  const u16* Kh = K + (size_t)bh * 2048 * 256;
  const u16* Vh = Vt + (size_t)bh * 256 * 2048;

  // staging: 8 waves x 2 chunks each for K and V (chunk c = wid*2+jj, 1KB)
  int krow[2], kcol[2], vrow[2], vcol[2];
#pragma unroll
  for (int jj = 0; jj < 2; ++jj) {
    int c = wid * 2 + jj;                // 0..15
    krow[jj] = 2 * c + (l >> 5);
    kcol[jj] = ((((l & 31) << 4) ^ ((krow[jj] & 7) << 4)) >> 1);
    vrow[jj] = c * 16 + (l >> 2);
    vcol[jj] = ((((l & 3) << 4) ^ (((vrow[jj] >> 1) & 3) << 4)) >> 1);
  }

  short8 qf[8];
#pragma unroll
  for (int kk = 0; kk < 8; ++kk)
    qf[kk] = *(const short8*)&Qh[(size_t)(qr + lc) * 256 + kk * 32 + lg * 8];

  f32x4 o[16];
#pragma unroll
  for (int nf = 0; nf < 16; ++nf) o[nf] = (f32x4)0.0f;
  float mrow = -1e30f;
  float lrow = 0.0f;  // per-lane partial; reduced once at epilogue

  uint32_t* Pw = (uint32_t*)P[wid];
  const u16* Pm = P[wid];

  const int ntiles = q0 / 32 + 4;

#pragma unroll
  for (int jj = 0; jj < 2; ++jj) {
    gld_lds16(Kh + (size_t)krow[jj] * 256 + kcol[jj], &Ks[0][(wid * 2 + jj) * 512]);
    gld_lds16(Vh + (size_t)vrow[jj] * 2048 + vcol[jj], &Vs[0][(wid * 2 + jj) * 512]);
  }
  __syncthreads();

  for (int t = 0; t < ntiles; ++t) {
    const int buf = t & 1;
    if (t + 1 < ntiles) {
      const int kv1 = (t + 1) << 5;
#pragma unroll
      for (int jj = 0; jj < 2; ++jj) {
        gld_lds16(Kh + (size_t)(kv1 + krow[jj]) * 256 + kcol[jj],
                  &Ks[buf ^ 1][(wid * 2 + jj) * 512]);
        gld_lds16(Vh + (size_t)vrow[jj] * 2048 + kv1 + vcol[jj],
                  &Vs[buf ^ 1][(wid * 2 + jj) * 512]);
      }
    }
    const int kv0 = t << 5;
    const char* KsB = (const char*)Ks[buf];
    const char* VsB = (const char*)Vs[buf];

    // ---- QK^T (swapped): D[kv][q] ----
    f32x4 s0 = (f32x4)0.0f, s1 = (f32x4)0.0f;
    __builtin_amdgcn_s_setprio(1);
#pragma unroll
    for (int kk = 0; kk < 8; ++kk) {
      const int cb = kk * 64 + lg * 16;
      short8 k0 = *(const short8*)(KsB + lc * 512 + (cb ^ ((lc & 7) << 4)));
      short8 k1 = *(const short8*)(KsB + (16 + lc) * 512 + (cb ^ ((lc & 7) << 4)));
      s0 = mfma16(k0, qf[kk], s0);
      s1 = mfma16(k1, qf[kk], s1);
    }
    __builtin_amdgcn_s_setprio(0);

    float sv[8];
#pragma unroll
    for (int r = 0; r < 4; ++r) { sv[r] = s0[r]; sv[4 + r] = s1[r]; }
    if (kv0 + 31 > qr) {
#pragma unroll
      for (int f = 0; f < 2; ++f)
#pragma unroll
        for (int r = 0; r < 4; ++r) {
          int kvg = kv0 + f * 16 + lg * 4 + r;
          if (kvg > qr + lc) sv[f * 4 + r] = -1e30f;
        }
    }
    float m8 = fmaxf(fmaxf(fmaxf(sv[0], sv[1]), fmaxf(sv[2], sv[3])),
                     fmaxf(fmaxf(sv[4], sv[5]), fmaxf(sv[6], sv[7])));
    float pm = fmaxf(m8, __shfl_xor(m8, 16));
    pm = fmaxf(pm, __shfl_xor(pm, 32));
    // defer-max: rescale only when some row's max grew by >8 (P stays <= 2^8)
    if (__ballot(pm > mrow + 8.0f)) {
      float mn = (pm > mrow + 8.0f) ? pm : mrow;
      float alpha = __builtin_amdgcn_exp2f(mrow - mn);
      lrow *= alpha;
      float aa[4];
#pragma unroll
      for (int r = 0; r < 4; ++r) aa[r] = __shfl(alpha, lg * 4 + r);
#pragma unroll
      for (int nf = 0; nf < 16; ++nf) {
        f32x4 t4 = o[nf];
#pragma unroll
        for (int r = 0; r < 4; ++r) t4[r] *= aa[r];
        o[nf] = t4;
      }
      mrow = mn;
    }
    float p[8];
#pragma unroll
    for (int jq = 0; jq < 8; ++jq) p[jq] = __builtin_amdgcn_exp2f(sv[jq] - mrow);
    lrow += ((p[0] + p[1]) + (p[2] + p[3])) + ((p[4] + p[5]) + (p[6] + p[7]));
    asm volatile("" ::: "memory");
    Pw[lc * 20 + lg * 2 + 0] = cvtpk_bf16(p[0], p[1]);
    Pw[lc * 20 + lg * 2 + 1] = cvtpk_bf16(p[2], p[3]);
    Pw[lc * 20 + 8 + lg * 2 + 0] = cvtpk_bf16(p[4], p[5]);
    Pw[lc * 20 + 8 + lg * 2 + 1] = cvtpk_bf16(p[6], p[7]);
    asm volatile("" ::: "memory");
    short8 pf = *(const short8*)&Pm[lc * 40 + lg * 8];
    // ---- PV from LDS V ----
    __builtin_amdgcn_s_setprio(1);
#pragma unroll
    for (int nf = 0; nf < 16; ++nf) {
      const int d = nf * 16 + lc;
      short8 vf = *(const short8*)(VsB + d * 64 + ((lg * 16) ^ (((d >> 1) & 3) << 4)));
      o[nf] = mfma16(pf, vf, o[nf]);
    }
    __builtin_amdgcn_s_setprio(0);
    asm volatile("" ::: "memory");
    __syncthreads();
  }

  float lt = lrow + __shfl_xor(lrow, 16);
  lt += __shfl_xor(lt, 32);
  float il = 1.0f / lt;
  float ia[4];
#pragma unroll
  for (int r = 0; r < 4; ++r) ia[r] = __shfl(il, lg * 4 + r);
  const int crow0 = (bh >> 4) * 2048 + qr;
  const int ccol0 = (bh & 15) * 256;
#pragma unroll
  for (int nf = 0; nf < 16; ++nf)
#pragma unroll
    for (int r = 0; r < 4; ++r)
      ctx[(size_t)(crow0 + lg * 4 + r) * 4096 + ccol0 + nf * 16 + lc] =
          f2bf(o[nf][r] * ia[r]);
}

// ---------- launcher ----------
extern "C" void kernel_launch(void* const* d_in, const int* in_sizes, int n_in,
                              void* d_out, int out_size, void* d_ws, size_t ws_size,
                              hipStream_t stream) {
  const float* hidden = (const float*)d_in[0];
  const float* Wq = (const float*)d_in[1];
  const float* Wk = (const float*)d_in[2];
  const float* Wv = (const float*)d_in[3];
  const float* Wo = (const float*)d_in[4];
  const int* pos = (const int*)d_in[5];

  const size_t NEL = 16777216;  // 4096*4096
  if (ws_size < 6 * NEL * sizeof(u16)) return;  // need 192 MB scratch

  u16* hb = (u16*)d_ws;      // hidden bf16; reused as ctx after QKV GEMMs
  u16* wq = hb + NEL;
  u16* wk = wq + NEL;
  u16* wv = wk + NEL;
  u16* wo = wv + NEL;
  u16* vt = wo + NEL;        // V^T [bh][d][s]
  u16* ctx = hb;
  u16* qb = (u16*)d_out;     // Q,K live in d_out; overwritten by final GEMM
  u16* kb = qb + NEL;

  cvt_bf16_5<<<40960, 256, 0, stream>>>(hidden, Wq, Wk, Wv, Wo, hb);

  // Q pre-scaled by log2(e)/16 so flash softmax runs in exp2 domain.
  gemm_nt<0><<<256, 512, 0, stream>>>(hb, wq, qb, 0.09016844f);
  gemm_nt<0><<<256, 512, 0, stream>>>(hb, wk, kb, 1.0f);
  gemm_nt<1><<<256, 512, 0, stream>>>(hb, wv, vt, 1.0f);

  rope_qk<<<16384, 256, 0, stream>>>(qb, kb, pos);

  flash_attn<<<512, 512, 0, stream>>>(qb, kb, vt, ctx);

  gemm_nt<2><<<256, 512, 0, stream>>>(ctx, wo, d_out, 1.0f);
}

// Round 14
// 711.396 us; speedup vs baseline: 1.0531x; 1.0025x over previous
//
#include <hip/hip_runtime.h>
#include <stdint.h>

// ---------- types ----------
typedef unsigned short u16;
typedef short short8 __attribute__((ext_vector_type(8)));
typedef __bf16 bf16x8 __attribute__((ext_vector_type(8)));
typedef float f32x4 __attribute__((ext_vector_type(4)));

__device__ __forceinline__ u16 f2bf(float f) {
  uint32_t u = __float_as_uint(f);
  u += 0x7fffu + ((u >> 16) & 1u);   // RNE
  return (u16)(u >> 16);
}
__device__ __forceinline__ float bf2f(u16 h) {
  return __uint_as_float(((uint32_t)h) << 16);
}
__device__ __forceinline__ f32x4 mfma16(short8 a, short8 b, f32x4 c) {
  return __builtin_amdgcn_mfma_f32_16x16x32_bf16(
      __builtin_bit_cast(bf16x8, a), __builtin_bit_cast(bf16x8, b), c, 0, 0, 0);
}
__device__ __forceinline__ uint32_t cvtpk_bf16(float lo, float hi) {
  uint32_t r;
  asm("v_cvt_pk_bf16_f32 %0, %1, %2" : "=v"(r) : "v"(lo), "v"(hi));
  return r;
}
// async global->LDS, 16B per lane; LDS dest must be the wave-uniform base.
__device__ __forceinline__ void gld_lds16(const u16* g, u16* lds_base) {
  __builtin_amdgcn_global_load_lds(
      (__attribute__((address_space(1))) void*)g,
      (__attribute__((address_space(3))) void*)lds_base, 16, 0, 0);
}
// raw barrier with compiler-only memory fence (no vmcnt/lgkmcnt drain!)
#define BAR() do { asm volatile("" ::: "memory"); \
                   __builtin_amdgcn_s_barrier(); \
                   asm volatile("" ::: "memory"); } while (0)

// ---------- fp32 -> bf16 convert, all 5 tensors in one launch ----------
__global__ __launch_bounds__(256) void cvt_bf16_5(const float* __restrict__ s0,
                                                  const float* __restrict__ s1,
                                                  const float* __restrict__ s2,
                                                  const float* __restrict__ s3,
                                                  const float* __restrict__ s4,
                                                  u16* __restrict__ dbase) {
  const int gb = blockIdx.x;          // 0..40959
  const int t = gb >> 13;             // tensor id 0..4 (8192 blocks each)
  const float* s = t == 0 ? s0 : t == 1 ? s1 : t == 2 ? s2 : t == 3 ? s3 : s4;
  u16* d = dbase + (size_t)t * 16777216;
  int i = (gb & 8191) * 256 + threadIdx.x;
  const float4* s4p = (const float4*)s;
  float4 a = s4p[2 * i], b = s4p[2 * i + 1];
  uint4 o;
  o.x = (uint32_t)f2bf(a.x) | ((uint32_t)f2bf(a.y) << 16);
  o.y = (uint32_t)f2bf(a.z) | ((uint32_t)f2bf(a.w) << 16);
  o.z = (uint32_t)f2bf(b.x) | ((uint32_t)f2bf(b.y) << 16);
  o.w = (uint32_t)f2bf(b.z) | ((uint32_t)f2bf(b.w) << 16);
  ((uint4*)d)[i] = o;
}

// ---------- NT GEMM, 256x256, 2 merged phases/K-tile (verified R7/R10, ~1215 TF) ----------
template <int MODE>
__global__ __launch_bounds__(512, 2) void gemm_nt(const u16* __restrict__ A,
                                                  const u16* __restrict__ W,
                                                  void* __restrict__ outp,
                                                  float oscale) {
  constexpr int Kd = 4096;
  __shared__ __align__(16) u16 As[2][2][8192];
  __shared__ __align__(16) u16 Bs[2][2][8192];
  const int tid = threadIdx.x;
  const int wid = tid >> 6, l = tid & 63;
  const int lg = (l >> 4) & 3, lc = l & 15;
  const int wm = wid >> 2, wn = wid & 3;  // 2 x 4 wave grid
  const int bid0 = blockIdx.x;
  const int bid = (bid0 & 7) * 32 + (bid0 >> 3);
  const int m0 = (bid >> 4) * 256, n0 = (bid & 15) * 256;

  const int srow = tid >> 3;                    // 0..63
  const int scol = ((tid & 7) ^ (srow & 7)) * 8;  // swizzled k-slot source, u16
  const int arow = m0 + srow;
  const int browb = n0 + ((srow >> 5) & 1) * 64 + (srow & 31);

#define STAGE_A(BUF, H, T) do { \
    const u16* g0 = A + (size_t)(arow + (H) * 64) * Kd + (T) * 64 + scol; \
    gld_lds16(g0, &As[BUF][H][wid * 512]); \
    gld_lds16(g0 + (size_t)128 * Kd, &As[BUF][H][4096 + wid * 512]); \
  } while (0)
#define STAGE_B(BUF, H, T) do { \
    const u16* g0 = W + (size_t)(browb + (H) * 32) * Kd + (T) * 64 + scol; \
    gld_lds16(g0, &Bs[BUF][H][wid * 512]); \
    gld_lds16(g0 + (size_t)128 * Kd, &Bs[BUF][H][4096 + wid * 512]); \
  } while (0)

  f32x4 acc[8][4];
#pragma unroll
  for (int i = 0; i < 8; ++i)
#pragma unroll
    for (int j = 0; j < 4; ++j) acc[i][j] = (f32x4)0.0f;

  const int axor = (lc & 7);

  short8 af[4][2], b0f[2][2], b1f[2][2];

#define LDA(MQ) do { \
    const char* Ab_ = (const char*)As[buf][MQ] + (wm * 64 + lc) * 128; \
    _Pragma("unroll") for (int f = 0; f < 4; ++f) \
      _Pragma("unroll") for (int kk = 0; kk < 2; ++kk) \
        af[f][kk] = *(const short8*)(Ab_ + f * 2048 + (((kk * 4 + lg) ^ axor) << 4)); \
  } while (0)
#define LDB(DST, NQ) do { \
    const char* Bb_ = (const char*)Bs[buf][NQ] + (wn * 32 + lc) * 128; \
    _Pragma("unroll") for (int g = 0; g < 2; ++g) \
      _Pragma("unroll") for (int kk = 0; kk < 2; ++kk) \
        DST[g][kk] = *(const short8*)(Bb_ + g * 2048 + (((kk * 4 + lg) ^ axor) << 4)); \
  } while (0)
#define MM(MQ, NQ, BF) do { \
    __builtin_amdgcn_s_setprio(1); \
    _Pragma("unroll") for (int f = 0; f < 4; ++f) \
      _Pragma("unroll") for (int g = 0; g < 2; ++g) \
        _Pragma("unroll") for (int kk = 0; kk < 2; ++kk) \
          acc[(MQ) * 4 + f][(NQ) * 2 + g] = \
              mfma16(af[f][kk], BF[g][kk], acc[(MQ) * 4 + f][(NQ) * 2 + g]); \
    __builtin_amdgcn_s_setprio(0); \
  } while (0)

  // prologue: K0's 4 units + A0(1),B1(1); retire K0; barrier.
  STAGE_A(0, 0, 0); STAGE_B(0, 1, 0); STAGE_B(0, 0, 0); STAGE_A(0, 1, 0);
  STAGE_A(1, 0, 1); STAGE_B(1, 1, 1);
  asm volatile("s_waitcnt vmcnt(4)" ::: "memory");
  BAR();

#pragma unroll 1
  for (int t = 0; t < 62; ++t) {
    const int buf = t & 1, nbuf = buf ^ 1;
    LDA(0); LDB(b0f, 0); LDB(b1f, 1);
    STAGE_B(nbuf, 0, t + 1); STAGE_A(nbuf, 1, t + 1);
    BAR(); MM(0, 0, b0f); MM(0, 1, b1f); BAR();
    LDA(1);
    STAGE_A(buf, 0, t + 2); STAGE_B(buf, 1, t + 2);
    asm volatile("s_waitcnt vmcnt(4)" ::: "memory");
    BAR(); MM(1, 1, b1f); MM(1, 0, b0f); BAR();
  }
  {  // t = 62: stage only K-tile 63's remaining units; full drain.
    const int buf = 0, nbuf = 1;
    LDA(0); LDB(b0f, 0); LDB(b1f, 1);
    STAGE_B(nbuf, 0, 63); STAGE_A(nbuf, 1, 63);
    BAR(); MM(0, 0, b0f); MM(0, 1, b1f); BAR();
    LDA(1);
    asm volatile("s_waitcnt vmcnt(0)" ::: "memory");
    BAR(); MM(1, 1, b1f); MM(1, 0, b0f); BAR();
  }
  {  // t = 63: no staging.
    const int buf = 1;
    LDA(0); LDB(b0f, 0); LDB(b1f, 1);
    BAR(); MM(0, 0, b0f); MM(0, 1, b1f); BAR();
    LDA(1);
    BAR(); MM(1, 1, b1f); MM(1, 0, b0f); BAR();
  }
#undef MM
#undef LDB
#undef LDA
#undef STAGE_A
#undef STAGE_B

  const int gr0 = m0 + wm * 128, gc0 = n0 + wn * 64;
#pragma unroll
  for (int mf = 0; mf < 8; ++mf)
#pragma unroll
    for (int nf = 0; nf < 4; ++nf)
#pragma unroll
      for (int r = 0; r < 4; ++r) {
        float v = acc[mf][nf][r] * oscale;
        int gr = gr0 + mf * 16 + lg * 4 + r;  // m index
        int gc = gc0 + nf * 16 + lc;          // n index
        if constexpr (MODE == 0) {
          ((u16*)outp)[((size_t)(((gr >> 11) * 16 + (gc >> 8)) * 2048 +
                                 (gr & 2047))) * 256 + (gc & 255)] = f2bf(v);
        } else if constexpr (MODE == 1) {
          ((u16*)outp)[(size_t)((gr >> 11) * 4096 + gc) * 2048 + (gr & 2047)] =
              f2bf(v);
        } else {
          ((float*)outp)[(size_t)gr * 4096 + gc] = v;
        }
      }
}

// ---------- GPT-J interleaved RoPE on Q,K (first 64 dims/head), in place ----------
__global__ __launch_bounds__(256) void rope_qk(u16* __restrict__ Qb,
                                               u16* __restrict__ Kb,
                                               const int* __restrict__ pos) {
  int idx = blockIdx.x * 256 + threadIdx.x;  // [2][32 bh][2048 s][32 pairs]
  int pair = idx & 31;
  int s = (idx >> 5) & 2047;
  int bh = (idx >> 16) & 31;
  u16* T = (idx >> 21) ? Kb : Qb;
  float p = (float)pos[s];
  float inv = __builtin_amdgcn_exp2f((float)pair * -0.41524101186407984f);
  float ang = p * inv, sn, cs;
  sincosf(ang, &sn, &cs);
  u16* base = T + ((size_t)bh * 2048 + s) * 256 + pair * 2;
  float x1 = bf2f(base[0]), x2 = bf2f(base[1]);
  base[0] = f2bf(x1 * cs - x2 * sn);
  base[1] = f2bf(x2 * cs + x1 * sn);
}

// ---------- causal flash attention v8: masked-tail wave skip ----------
// R13 structure (8-wave/128-row blocks, mirrored qi pairing). ONE change:
// waves whose current KV tile is fully masked (kv0 > qr+15) skip the tile
// body (QK/softmax/P/PV) with a wave-uniform branch. Staging and
// __syncthreads() stay OUTSIDE the branch -> barrier/drain contract
// identical. Skipped tiles contributed exactly p=0 before, so numerics are
// bit-identical. Recovers the ~4.4% of tile-slots wasted on masked tails
// (block-uniform ntiles covers wave 7; waves 0-6 over-run by up to 3 tiles).
__global__ __launch_bounds__(512, 2) void flash_attn(const u16* __restrict__ Q,
                                                     const u16* __restrict__ K,
                                                     const u16* __restrict__ Vt,
                                                     u16* __restrict__ ctx) {
  __shared__ u16 Ks[2][32 * 256];
  __shared__ u16 Vs[2][256 * 32];
  __shared__ u16 P[8][16 * 40];

  const int bid = blockIdx.x;            // 0..511
  const int xcd = bid & 7, j = bid >> 3; // j = 0..63 within XCD
  const int hl = (j >> 5) * 2 + ((j >> 4) & 1);  // head 0..3 in XCD
  const int r_ = j & 15;
  const int qi = (j < 32) ? r_ : (15 - r_);      // mirrored second half
  const int bh = xcd * 4 + hl;
  const int q0 = 1920 - qi * 128;        // 128-row q block
  const int tid = threadIdx.x;
  const int wid = tid >> 6, l = tid & 63;
  const int lg = l >> 4, lc = l & 15;
  const int qr = q0 + wid * 16;

  const u16* Qh = Q + (size_t)bh * 2048 * 256;
  const u16* Kh = K + (size_t)bh * 2048 * 256;
  const u16* Vh = Vt + (size_t)bh * 256 * 2048;

  // staging: 8 waves x 2 chunks each for K and V (chunk c = wid*2+jj, 1KB)
  int krow[2], kcol[2], vrow[2], vcol[2];
#pragma unroll
  for (int jj = 0; jj < 2; ++jj) {
    int c = wid * 2 + jj;                // 0..15
    krow[jj] = 2 * c + (l >> 5);
    kcol[jj] = ((((l & 31) << 4) ^ ((krow[jj] & 7) << 4)) >> 1);
    vrow[jj] = c * 16 + (l >> 2);
    vcol[jj] = ((((l & 3) << 4) ^ (((vrow[jj] >> 1) & 3) << 4)) >> 1);
  }

  short8 qf[8];
#pragma unroll
  for (int kk = 0; kk < 8; ++kk)
    qf[kk] = *(const short8*)&Qh[(size_t)(qr + lc) * 256 + kk * 32 + lg * 8];

  f32x4 o[16];
#pragma unroll
  for (int nf = 0; nf < 16; ++nf) o[nf] = (f32x4)0.0f;
  float mrow = -1e30f;
  float lrow = 0.0f;  // per-lane partial; reduced once at epilogue

  uint32_t* Pw = (uint32_t*)P[wid];
  const u16* Pm = P[wid];

  const int ntiles = q0 / 32 + 4;

#pragma unroll
  for (int jj = 0; jj < 2; ++jj) {
    gld_lds16(Kh + (size_t)krow[jj] * 256 + kcol[jj], &Ks[0][(wid * 2 + jj) * 512]);
    gld_lds16(Vh + (size_t)vrow[jj] * 2048 + vcol[jj], &Vs[0][(wid * 2 + jj) * 512]);
  }
  __syncthreads();

  for (int t = 0; t < ntiles; ++t) {
    const int buf = t & 1;
    if (t + 1 < ntiles) {
      const int kv1 = (t + 1) << 5;
#pragma unroll
      for (int jj = 0; jj < 2; ++jj) {
        gld_lds16(Kh + (size_t)(kv1 + krow[jj]) * 256 + kcol[jj],
                  &Ks[buf ^ 1][(wid * 2 + jj) * 512]);
        gld_lds16(Vh + (size_t)vrow[jj] * 2048 + kv1 + vcol[jj],
                  &Vs[buf ^ 1][(wid * 2 + jj) * 512]);
      }
    }
    const int kv0 = t << 5;
    // wave-uniform skip of fully-masked tail tiles (would contribute p=0)
    if (kv0 <= qr + 15) {
      const char* KsB = (const char*)Ks[buf];
      const char* VsB = (const char*)Vs[buf];

      // ---- QK^T (swapped): D[kv][q] ----
      f32x4 s0 = (f32x4)0.0f, s1 = (f32x4)0.0f;
      __builtin_amdgcn_s_setprio(1);
#pragma unroll
      for (int kk = 0; kk < 8; ++kk) {
        const int cb = kk * 64 + lg * 16;
        short8 k0 = *(const short8*)(KsB + lc * 512 + (cb ^ ((lc & 7) << 4)));
        short8 k1 = *(const short8*)(KsB + (16 + lc) * 512 + (cb ^ ((lc & 7) << 4)));
        s0 = mfma16(k0, qf[kk], s0);
        s1 = mfma16(k1, qf[kk], s1);
      }
      __builtin_amdgcn_s_setprio(0);

      float sv[8];
#pragma unroll
      for (int r = 0; r < 4; ++r) { sv[r] = s0[r]; sv[4 + r] = s1[r]; }
      if (kv0 + 31 > qr) {
#pragma unroll
        for (int f = 0; f < 2; ++f)
#pragma unroll
          for (int r = 0; r < 4; ++r) {
            int kvg = kv0 + f * 16 + lg * 4 + r;
            if (kvg > qr + lc) sv[f * 4 + r] = -1e30f;
          }
      }
      float m8 = fmaxf(fmaxf(fmaxf(sv[0], sv[1]), fmaxf(sv[2], sv[3])),
                       fmaxf(fmaxf(sv[4], sv[5]), fmaxf(sv[6], sv[7])));
      float pm = fmaxf(m8, __shfl_xor(m8, 16));
      pm = fmaxf(pm, __shfl_xor(pm, 32));
      // defer-max: rescale only when some row's max grew by >8 (P <= 2^8)
      if (__ballot(pm > mrow + 8.0f)) {
        float mn = (pm > mrow + 8.0f) ? pm : mrow;
        float alpha = __builtin_amdgcn_exp2f(mrow - mn);
        lrow *= alpha;
        float aa[4];
#pragma unroll
        for (int r = 0; r < 4; ++r) aa[r] = __shfl(alpha, lg * 4 + r);
#pragma unroll
        for (int nf = 0; nf < 16; ++nf) {
          f32x4 t4 = o[nf];
#pragma unroll
          for (int r = 0; r < 4; ++r) t4[r] *= aa[r];
          o[nf] = t4;
        }
        mrow = mn;
      }
      float p[8];
#pragma unroll
      for (int jq = 0; jq < 8; ++jq) p[jq] = __builtin_amdgcn_exp2f(sv[jq] - mrow);
      lrow += ((p[0] + p[1]) + (p[2] + p[3])) + ((p[4] + p[5]) + (p[6] + p[7]));
      asm volatile("" ::: "memory");
      Pw[lc * 20 + lg * 2 + 0] = cvtpk_bf16(p[0], p[1]);
      Pw[lc * 20 + lg * 2 + 1] = cvtpk_bf16(p[2], p[3]);
      Pw[lc * 20 + 8 + lg * 2 + 0] = cvtpk_bf16(p[4], p[5]);
      Pw[lc * 20 + 8 + lg * 2 + 1] = cvtpk_bf16(p[6], p[7]);
      asm volatile("" ::: "memory");
      short8 pf = *(const short8*)&Pm[lc * 40 + lg * 8];
      // ---- PV from LDS V ----
      __builtin_amdgcn_s_setprio(1);
#pragma unroll
      for (int nf = 0; nf < 16; ++nf) {
        const int d = nf * 16 + lc;
        short8 vf = *(const short8*)(VsB + d * 64 + ((lg * 16) ^ (((d >> 1) & 3) << 4)));
        o[nf] = mfma16(pf, vf, o[nf]);
      }
      __builtin_amdgcn_s_setprio(0);
      asm volatile("" ::: "memory");
    }
    __syncthreads();
  }

  float lt = lrow + __shfl_xor(lrow, 16);
  lt += __shfl_xor(lt, 32);
  float il = 1.0f / lt;
  float ia[4];
#pragma unroll
  for (int r = 0; r < 4; ++r) ia[r] = __shfl(il, lg * 4 + r);
  const int crow0 = (bh >> 4) * 2048 + qr;
  const int ccol0 = (bh & 15) * 256;
#pragma unroll
  for (int nf = 0; nf < 16; ++nf)
#pragma unroll
    for (int r = 0; r < 4; ++r)
      ctx[(size_t)(crow0 + lg * 4 + r) * 4096 + ccol0 + nf * 16 + lc] =
          f2bf(o[nf][r] * ia[r]);
}

// ---------- launcher ----------
extern "C" void kernel_launch(void* const* d_in, const int* in_sizes, int n_in,
                              void* d_out, int out_size, void* d_ws, size_t ws_size,
                              hipStream_t stream) {
  const float* hidden = (const float*)d_in[0];
  const float* Wq = (const float*)d_in[1];
  const float* Wk = (const float*)d_in[2];
  const float* Wv = (const float*)d_in[3];
  const float* Wo = (const float*)d_in[4];
  const int* pos = (const int*)d_in[5];

  const size_t NEL = 16777216;  // 4096*4096
  if (ws_size < 6 * NEL * sizeof(u16)) return;  // need 192 MB scratch

  u16* hb = (u16*)d_ws;      // hidden bf16; reused as ctx after QKV GEMMs
  u16* wq = hb + NEL;
  u16* wk = wq + NEL;
  u16* wv = wk + NEL;
  u16* wo = wv + NEL;
  u16* vt = wo + NEL;        // V^T [bh][d][s]
  u16* ctx = hb;
  u16* qb = (u16*)d_out;     // Q,K live in d_out; overwritten by final GEMM
  u16* kb = qb + NEL;

  cvt_bf16_5<<<40960, 256, 0, stream>>>(hidden, Wq, Wk, Wv, Wo, hb);

  // Q pre-scaled by log2(e)/16 so flash softmax runs in exp2 domain.
  gemm_nt<0><<<256, 512, 0, stream>>>(hb, wq, qb, 0.09016844f);
  gemm_nt<0><<<256, 512, 0, stream>>>(hb, wk, kb, 1.0f);
  gemm_nt<1><<<256, 512, 0, stream>>>(hb, wv, vt, 1.0f);

  rope_qk<<<16384, 256, 0, stream>>>(qb, kb, pos);

  flash_attn<<<512, 512, 0, stream>>>(qb, kb, vt, ctx);

  gemm_nt<2><<<256, 512, 0, stream>>>(ctx, wo, d_out, 1.0f);
}

// Round 15
// 708.322 us; speedup vs baseline: 1.0577x; 1.0043x over previous
//
#include <hip/hip_runtime.h>
#include <stdint.h>

// ---------- types ----------
typedef unsigned short u16;
typedef short short8 __attribute__((ext_vector_type(8)));
typedef __bf16 bf16x8 __attribute__((ext_vector_type(8)));
typedef float f32x4 __attribute__((ext_vector_type(4)));

__device__ __forceinline__ u16 f2bf(float f) {
  uint32_t u = __float_as_uint(f);
  u += 0x7fffu + ((u >> 16) & 1u);   // RNE
  return (u16)(u >> 16);
}
__device__ __forceinline__ float bf2f(u16 h) {
  return __uint_as_float(((uint32_t)h) << 16);
}
__device__ __forceinline__ f32x4 mfma16(short8 a, short8 b, f32x4 c) {
  return __builtin_amdgcn_mfma_f32_16x16x32_bf16(
      __builtin_bit_cast(bf16x8, a), __builtin_bit_cast(bf16x8, b), c, 0, 0, 0);
}
__device__ __forceinline__ uint32_t cvtpk_bf16(float lo, float hi) {
  uint32_t r;
  asm("v_cvt_pk_bf16_f32 %0, %1, %2" : "=v"(r) : "v"(lo), "v"(hi));
  return r;
}
// async global->LDS, 16B per lane; LDS dest must be the wave-uniform base.
__device__ __forceinline__ void gld_lds16(const u16* g, u16* lds_base) {
  __builtin_amdgcn_global_load_lds(
      (__attribute__((address_space(1))) void*)g,
      (__attribute__((address_space(3))) void*)lds_base, 16, 0, 0);
}
// raw barrier with compiler-only memory fence (no vmcnt/lgkmcnt drain!)
#define BAR() do { asm volatile("" ::: "memory"); \
                   __builtin_amdgcn_s_barrier(); \
                   asm volatile("" ::: "memory"); } while (0)

// ---------- fp32 -> bf16 convert, all 5 tensors in one launch ----------
__global__ __launch_bounds__(256) void cvt_bf16_5(const float* __restrict__ s0,
                                                  const float* __restrict__ s1,
                                                  const float* __restrict__ s2,
                                                  const float* __restrict__ s3,
                                                  const float* __restrict__ s4,
                                                  u16* __restrict__ dbase) {
  const int gb = blockIdx.x;          // 0..40959
  const int t = gb >> 13;             // tensor id 0..4 (8192 blocks each)
  const float* s = t == 0 ? s0 : t == 1 ? s1 : t == 2 ? s2 : t == 3 ? s3 : s4;
  u16* d = dbase + (size_t)t * 16777216;
  int i = (gb & 8191) * 256 + threadIdx.x;
  const float4* s4p = (const float4*)s;
  float4 a = s4p[2 * i], b = s4p[2 * i + 1];
  uint4 o;
  o.x = (uint32_t)f2bf(a.x) | ((uint32_t)f2bf(a.y) << 16);
  o.y = (uint32_t)f2bf(a.z) | ((uint32_t)f2bf(a.w) << 16);
  o.z = (uint32_t)f2bf(b.x) | ((uint32_t)f2bf(b.y) << 16);
  o.w = (uint32_t)f2bf(b.z) | ((uint32_t)f2bf(b.w) << 16);
  ((uint4*)d)[i] = o;
}

// ---------- merged QKV NT GEMM: 768 blocks = 3 tensors x 256 tiles ----------
// Inner loop byte-identical to the verified R7/R10 2-phase schedule (~1215 TF).
// Block-uniform tensor select: W = Wbase + tsr*NEL (wq,wk,wv contiguous);
// Q/K out MODE0 to outQK + tsr*NEL (qb,kb contiguous); V out MODE1 to vt.
// Removes 2 launch boundaries; K/V blocks backfill finished CUs.
// Per-XCD order: all of Q's chunks, then K's, then V's (L2 locality kept).
__global__ __launch_bounds__(512, 2) void gemm_qkv(const u16* __restrict__ A,
                                                   const u16* __restrict__ Wbase,
                                                   u16* __restrict__ outQK,
                                                   u16* __restrict__ outV,
                                                   float qscale) {
  constexpr int Kd = 4096;
  constexpr size_t NEL = 16777216;
  __shared__ __align__(16) u16 As[2][2][8192];
  __shared__ __align__(16) u16 Bs[2][2][8192];
  const int tid = threadIdx.x;
  const int wid = tid >> 6, l = tid & 63;
  const int lg = (l >> 4) & 3, lc = l & 15;
  const int wm = wid >> 2, wn = wid & 3;  // 2 x 4 wave grid
  const int bid0 = blockIdx.x;            // 0..767
  const int xcd = bid0 & 7;
  const int r = bid0 >> 3;                // 0..95
  const int tsr = r >> 5;                 // tensor 0=Q 1=K 2=V
  const int bid = xcd * 32 + (r & 31);    // tile 0..255 within tensor
  const int m0 = (bid >> 4) * 256, n0 = (bid & 15) * 256;
  const u16* W = Wbase + (size_t)tsr * NEL;
  const float oscale = (tsr == 0) ? qscale : 1.0f;

  const int srow = tid >> 3;                    // 0..63
  const int scol = ((tid & 7) ^ (srow & 7)) * 8;  // swizzled k-slot source, u16
  const int arow = m0 + srow;
  const int browb = n0 + ((srow >> 5) & 1) * 64 + (srow & 31);

#define STAGE_A(BUF, H, T) do { \
    const u16* g0 = A + (size_t)(arow + (H) * 64) * Kd + (T) * 64 + scol; \
    gld_lds16(g0, &As[BUF][H][wid * 512]); \
    gld_lds16(g0 + (size_t)128 * Kd, &As[BUF][H][4096 + wid * 512]); \
  } while (0)
#define STAGE_B(BUF, H, T) do { \
    const u16* g0 = W + (size_t)(browb + (H) * 32) * Kd + (T) * 64 + scol; \
    gld_lds16(g0, &Bs[BUF][H][wid * 512]); \
    gld_lds16(g0 + (size_t)128 * Kd, &Bs[BUF][H][4096 + wid * 512]); \
  } while (0)

  f32x4 acc[8][4];
#pragma unroll
  for (int i = 0; i < 8; ++i)
#pragma unroll
    for (int j = 0; j < 4; ++j) acc[i][j] = (f32x4)0.0f;

  const int axor = (lc & 7);

  short8 af[4][2], b0f[2][2], b1f[2][2];

#define LDA(MQ) do { \
    const char* Ab_ = (const char*)As[buf][MQ] + (wm * 64 + lc) * 128; \
    _Pragma("unroll") for (int f = 0; f < 4; ++f) \
      _Pragma("unroll") for (int kk = 0; kk < 2; ++kk) \
        af[f][kk] = *(const short8*)(Ab_ + f * 2048 + (((kk * 4 + lg) ^ axor) << 4)); \
  } while (0)
#define LDB(DST, NQ) do { \
    const char* Bb_ = (const char*)Bs[buf][NQ] + (wn * 32 + lc) * 128; \
    _Pragma("unroll") for (int g = 0; g < 2; ++g) \
      _Pragma("unroll") for (int kk = 0; kk < 2; ++kk) \
        DST[g][kk] = *(const short8*)(Bb_ + g * 2048 + (((kk * 4 + lg) ^ axor) << 4)); \
  } while (0)
#define MM(MQ, NQ, BF) do { \
    __builtin_amdgcn_s_setprio(1); \
    _Pragma("unroll") for (int f = 0; f < 4; ++f) \
      _Pragma("unroll") for (int g = 0; g < 2; ++g) \
        _Pragma("unroll") for (int kk = 0; kk < 2; ++kk) \
          acc[(MQ) * 4 + f][(NQ) * 2 + g] = \
              mfma16(af[f][kk], BF[g][kk], acc[(MQ) * 4 + f][(NQ) * 2 + g]); \
    __builtin_amdgcn_s_setprio(0); \
  } while (0)

  // prologue: K0's 4 units + A0(1),B1(1); retire K0; barrier.
  STAGE_A(0, 0, 0); STAGE_B(0, 1, 0); STAGE_B(0, 0, 0); STAGE_A(0, 1, 0);
  STAGE_A(1, 0, 1); STAGE_B(1, 1, 1);
  asm volatile("s_waitcnt vmcnt(4)" ::: "memory");
  BAR();

#pragma unroll 1
  for (int t = 0; t < 62; ++t) {
    const int buf = t & 1, nbuf = buf ^ 1;
    LDA(0); LDB(b0f, 0); LDB(b1f, 1);
    STAGE_B(nbuf, 0, t + 1); STAGE_A(nbuf, 1, t + 1);
    BAR(); MM(0, 0, b0f); MM(0, 1, b1f); BAR();
    LDA(1);
    STAGE_A(buf, 0, t + 2); STAGE_B(buf, 1, t + 2);
    asm volatile("s_waitcnt vmcnt(4)" ::: "memory");
    BAR(); MM(1, 1, b1f); MM(1, 0, b0f); BAR();
  }
  {  // t = 62: stage only K-tile 63's remaining units; full drain.
    const int buf = 0, nbuf = 1;
    LDA(0); LDB(b0f, 0); LDB(b1f, 1);
    STAGE_B(nbuf, 0, 63); STAGE_A(nbuf, 1, 63);
    BAR(); MM(0, 0, b0f); MM(0, 1, b1f); BAR();
    LDA(1);
    asm volatile("s_waitcnt vmcnt(0)" ::: "memory");
    BAR(); MM(1, 1, b1f); MM(1, 0, b0f); BAR();
  }
  {  // t = 63: no staging.
    const int buf = 1;
    LDA(0); LDB(b0f, 0); LDB(b1f, 1);
    BAR(); MM(0, 0, b0f); MM(0, 1, b1f); BAR();
    LDA(1);
    BAR(); MM(1, 1, b1f); MM(1, 0, b0f); BAR();
  }
#undef MM
#undef LDB
#undef LDA
#undef STAGE_A
#undef STAGE_B

  const int gr0 = m0 + wm * 128, gc0 = n0 + wn * 64;
  if (tsr < 2) {
    u16* outp = outQK + (size_t)tsr * NEL;
#pragma unroll
    for (int mf = 0; mf < 8; ++mf)
#pragma unroll
      for (int nf = 0; nf < 4; ++nf)
#pragma unroll
        for (int r4 = 0; r4 < 4; ++r4) {
          float v = acc[mf][nf][r4] * oscale;
          int gr = gr0 + mf * 16 + lg * 4 + r4;
          int gc = gc0 + nf * 16 + lc;
          outp[((size_t)(((gr >> 11) * 16 + (gc >> 8)) * 2048 +
                         (gr & 2047))) * 256 + (gc & 255)] = f2bf(v);
        }
  } else {
#pragma unroll
    for (int mf = 0; mf < 8; ++mf)
#pragma unroll
      for (int nf = 0; nf < 4; ++nf)
#pragma unroll
        for (int r4 = 0; r4 < 4; ++r4) {
          float v = acc[mf][nf][r4];
          int gr = gr0 + mf * 16 + lg * 4 + r4;
          int gc = gc0 + nf * 16 + lc;
          outV[(size_t)((gr >> 11) * 4096 + gc) * 2048 + (gr & 2047)] = f2bf(v);
        }
  }
}

// ---------- final NT GEMM (Wo), fp32 out (verified R7/R10 schedule) ----------
__global__ __launch_bounds__(512, 2) void gemm_wo(const u16* __restrict__ A,
                                                  const u16* __restrict__ W,
                                                  float* __restrict__ outp) {
  constexpr int Kd = 4096;
  __shared__ __align__(16) u16 As[2][2][8192];
  __shared__ __align__(16) u16 Bs[2][2][8192];
  const int tid = threadIdx.x;
  const int wid = tid >> 6, l = tid & 63;
  const int lg = (l >> 4) & 3, lc = l & 15;
  const int wm = wid >> 2, wn = wid & 3;
  const int bid0 = blockIdx.x;
  const int bid = (bid0 & 7) * 32 + (bid0 >> 3);
  const int m0 = (bid >> 4) * 256, n0 = (bid & 15) * 256;

  const int srow = tid >> 3;
  const int scol = ((tid & 7) ^ (srow & 7)) * 8;
  const int arow = m0 + srow;
  const int browb = n0 + ((srow >> 5) & 1) * 64 + (srow & 31);

#define STAGE_A(BUF, H, T) do { \
    const u16* g0 = A + (size_t)(arow + (H) * 64) * Kd + (T) * 64 + scol; \
    gld_lds16(g0, &As[BUF][H][wid * 512]); \
    gld_lds16(g0 + (size_t)128 * Kd, &As[BUF][H][4096 + wid * 512]); \
  } while (0)
#define STAGE_B(BUF, H, T) do { \
    const u16* g0 = W + (size_t)(browb + (H) * 32) * Kd + (T) * 64 + scol; \
    gld_lds16(g0, &Bs[BUF][H][wid * 512]); \
    gld_lds16(g0 + (size_t)128 * Kd, &Bs[BUF][H][4096 + wid * 512]); \
  } while (0)

  f32x4 acc[8][4];
#pragma unroll
  for (int i = 0; i < 8; ++i)
#pragma unroll
    for (int j = 0; j < 4; ++j) acc[i][j] = (f32x4)0.0f;

  const int axor = (lc & 7);
  short8 af[4][2], b0f[2][2], b1f[2][2];

#define LDA(MQ) do { \
    const char* Ab_ = (const char*)As[buf][MQ] + (wm * 64 + lc) * 128; \
    _Pragma("unroll") for (int f = 0; f < 4; ++f) \
      _Pragma("unroll") for (int kk = 0; kk < 2; ++kk) \
        af[f][kk] = *(const short8*)(Ab_ + f * 2048 + (((kk * 4 + lg) ^ axor) << 4)); \
  } while (0)
#define LDB(DST, NQ) do { \
    const char* Bb_ = (const char*)Bs[buf][NQ] + (wn * 32 + lc) * 128; \
    _Pragma("unroll") for (int g = 0; g < 2; ++g) \
      _Pragma("unroll") for (int kk = 0; kk < 2; ++kk) \
        DST[g][kk] = *(const short8*)(Bb_ + g * 2048 + (((kk * 4 + lg) ^ axor) << 4)); \
  } while (0)
#define MM(MQ, NQ, BF) do { \
    __builtin_amdgcn_s_setprio(1); \
    _Pragma("unroll") for (int f = 0; f < 4; ++f) \
      _Pragma("unroll") for (int g = 0; g < 2; ++g) \
        _Pragma("unroll") for (int kk = 0; kk < 2; ++kk) \
          acc[(MQ) * 4 + f][(NQ) * 2 + g] = \
              mfma16(af[f][kk], BF[g][kk], acc[(MQ) * 4 + f][(NQ) * 2 + g]); \
    __builtin_amdgcn_s_setprio(0); \
  } while (0)

  STAGE_A(0, 0, 0); STAGE_B(0, 1, 0); STAGE_B(0, 0, 0); STAGE_A(0, 1, 0);
  STAGE_A(1, 0, 1); STAGE_B(1, 1, 1);
  asm volatile("s_waitcnt vmcnt(4)" ::: "memory");
  BAR();

#pragma unroll 1
  for (int t = 0; t < 62; ++t) {
    const int buf = t & 1, nbuf = buf ^ 1;
    LDA(0); LDB(b0f, 0); LDB(b1f, 1);
    STAGE_B(nbuf, 0, t + 1); STAGE_A(nbuf, 1, t + 1);
    BAR(); MM(0, 0, b0f); MM(0, 1, b1f); BAR();
    LDA(1);
    STAGE_A(buf, 0, t + 2); STAGE_B(buf, 1, t + 2);
    asm volatile("s_waitcnt vmcnt(4)" ::: "memory");
    BAR(); MM(1, 1, b1f); MM(1, 0, b0f); BAR();
  }
  {
    const int buf = 0, nbuf = 1;
    LDA(0); LDB(b0f, 0); LDB(b1f, 1);
    STAGE_B(nbuf, 0, 63); STAGE_A(nbuf, 1, 63);
    BAR(); MM(0, 0, b0f); MM(0, 1, b1f); BAR();
    LDA(1);
    asm volatile("s_waitcnt vmcnt(0)" ::: "memory");
    BAR(); MM(1, 1, b1f); MM(1, 0, b0f); BAR();
  }
  {
    const int buf = 1;
    LDA(0); LDB(b0f, 0); LDB(b1f, 1);
    BAR(); MM(0, 0, b0f); MM(0, 1, b1f); BAR();
    LDA(1);
    BAR(); MM(1, 1, b1f); MM(1, 0, b0f); BAR();
  }
#undef MM
#undef LDB
#undef LDA
#undef STAGE_A
#undef STAGE_B

  const int gr0 = m0 + wm * 128, gc0 = n0 + wn * 64;
#pragma unroll
  for (int mf = 0; mf < 8; ++mf)
#pragma unroll
    for (int nf = 0; nf < 4; ++nf)
#pragma unroll
      for (int r4 = 0; r4 < 4; ++r4) {
        int gr = gr0 + mf * 16 + lg * 4 + r4;
        int gc = gc0 + nf * 16 + lc;
        outp[(size_t)gr * 4096 + gc] = acc[mf][nf][r4];
      }
}

// ---------- GPT-J interleaved RoPE on Q,K (first 64 dims/head), in place ----------
__global__ __launch_bounds__(256) void rope_qk(u16* __restrict__ Qb,
                                               u16* __restrict__ Kb,
                                               const int* __restrict__ pos) {
  int idx = blockIdx.x * 256 + threadIdx.x;  // [2][32 bh][2048 s][32 pairs]
  int pair = idx & 31;
  int s = (idx >> 5) & 2047;
  int bh = (idx >> 16) & 31;
  u16* T = (idx >> 21) ? Kb : Qb;
  float p = (float)pos[s];
  float inv = __builtin_amdgcn_exp2f((float)pair * -0.41524101186407984f);
  float ang = p * inv, sn, cs;
  sincosf(ang, &sn, &cs);
  u16* base = T + ((size_t)bh * 2048 + s) * 256 + pair * 2;
  float x1 = bf2f(base[0]), x2 = bf2f(base[1]);
  base[0] = f2bf(x1 * cs - x2 * sn);
  base[1] = f2bf(x2 * cs + x1 * sn);
}

// ---------- causal flash attention (verified R13/R14: ~190us) ----------
__global__ __launch_bounds__(512, 2) void flash_attn(const u16* __restrict__ Q,
                                                     const u16* __restrict__ K,
                                                     const u16* __restrict__ Vt,
                                                     u16* __restrict__ ctx) {
  __shared__ u16 Ks[2][32 * 256];
  __shared__ u16 Vs[2][256 * 32];
  __shared__ u16 P[8][16 * 40];

  const int bid = blockIdx.x;            // 0..511
  const int xcd = bid & 7, j = bid >> 3; // j = 0..63 within XCD
  const int hl = (j >> 5) * 2 + ((j >> 4) & 1);  // head 0..3 in XCD
  const int r_ = j & 15;
  const int qi = (j < 32) ? r_ : (15 - r_);      // mirrored second half
  const int bh = xcd * 4 + hl;
  const int q0 = 1920 - qi * 128;        // 128-row q block
  const int tid = threadIdx.x;
  const int wid = tid >> 6, l = tid & 63;
  const int lg = l >> 4, lc = l & 15;
  const int qr = q0 + wid * 16;

  const u16* Qh = Q + (size_t)bh * 2048 * 256;
  const u16* Kh = K + (size_t)bh * 2048 * 256;
  const u16* Vh = Vt + (size_t)bh * 256 * 2048;

  int krow[2], kcol[2], vrow[2], vcol[2];
#pragma unroll
  for (int jj = 0; jj < 2; ++jj) {
    int c = wid * 2 + jj;                // 0..15
    krow[jj] = 2 * c + (l >> 5);
    kcol[jj] = ((((l & 31) << 4) ^ ((krow[jj] & 7) << 4)) >> 1);
    vrow[jj] = c * 16 + (l >> 2);
    vcol[jj] = ((((l & 3) << 4) ^ (((vrow[jj] >> 1) & 3) << 4)) >> 1);
  }

  short8 qf[8];
#pragma unroll
  for (int kk = 0; kk < 8; ++kk)
    qf[kk] = *(const short8*)&Qh[(size_t)(qr + lc) * 256 + kk * 32 + lg * 8];

  f32x4 o[16];
#pragma unroll
  for (int nf = 0; nf < 16; ++nf) o[nf] = (f32x4)0.0f;
  float mrow = -1e30f;
  float lrow = 0.0f;

  uint32_t* Pw = (uint32_t*)P[wid];
  const u16* Pm = P[wid];

  const int ntiles = q0 / 32 + 4;

#pragma unroll
  for (int jj = 0; jj < 2; ++jj) {
    gld_lds16(Kh + (size_t)krow[jj] * 256 + kcol[jj], &Ks[0][(wid * 2 + jj) * 512]);
    gld_lds16(Vh + (size_t)vrow[jj] * 2048 + vcol[jj], &Vs[0][(wid * 2 + jj) * 512]);
  }
  __syncthreads();

  for (int t = 0; t < ntiles; ++t) {
    const int buf = t & 1;
    if (t + 1 < ntiles) {
      const int kv1 = (t + 1) << 5;
#pragma unroll
      for (int jj = 0; jj < 2; ++jj) {
        gld_lds16(Kh + (size_t)(kv1 + krow[jj]) * 256 + kcol[jj],
                  &Ks[buf ^ 1][(wid * 2 + jj) * 512]);
        gld_lds16(Vh + (size_t)vrow[jj] * 2048 + kv1 + vcol[jj],
                  &Vs[buf ^ 1][(wid * 2 + jj) * 512]);
      }
    }
    const int kv0 = t << 5;
    if (kv0 <= qr + 15) {
      const char* KsB = (const char*)Ks[buf];
      const char* VsB = (const char*)Vs[buf];

      f32x4 s0 = (f32x4)0.0f, s1 = (f32x4)0.0f;
      __builtin_amdgcn_s_setprio(1);
#pragma unroll
      for (int kk = 0; kk < 8; ++kk) {
        const int cb = kk * 64 + lg * 16;
        short8 k0 = *(const short8*)(KsB + lc * 512 + (cb ^ ((lc & 7) << 4)));
        short8 k1 = *(const short8*)(KsB + (16 + lc) * 512 + (cb ^ ((lc & 7) << 4)));
        s0 = mfma16(k0, qf[kk], s0);
        s1 = mfma16(k1, qf[kk], s1);
      }
      __builtin_amdgcn_s_setprio(0);

      float sv[8];
#pragma unroll
      for (int r4 = 0; r4 < 4; ++r4) { sv[r4] = s0[r4]; sv[4 + r4] = s1[r4]; }
      if (kv0 + 31 > qr) {
#pragma unroll
        for (int f = 0; f < 2; ++f)
#pragma unroll
          for (int r4 = 0; r4 < 4; ++r4) {
            int kvg = kv0 + f * 16 + lg * 4 + r4;
            if (kvg > qr + lc) sv[f * 4 + r4] = -1e30f;
          }
      }
      float m8 = fmaxf(fmaxf(fmaxf(sv[0], sv[1]), fmaxf(sv[2], sv[3])),
                       fmaxf(fmaxf(sv[4], sv[5]), fmaxf(sv[6], sv[7])));
      float pm = fmaxf(m8, __shfl_xor(m8, 16));
      pm = fmaxf(pm, __shfl_xor(pm, 32));
      if (__ballot(pm > mrow + 8.0f)) {
        float mn = (pm > mrow + 8.0f) ? pm : mrow;
        float alpha = __builtin_amdgcn_exp2f(mrow - mn);
        lrow *= alpha;
        float aa[4];
#pragma unroll
        for (int r4 = 0; r4 < 4; ++r4) aa[r4] = __shfl(alpha, lg * 4 + r4);
#pragma unroll
        for (int nf = 0; nf < 16; ++nf) {
          f32x4 t4 = o[nf];
#pragma unroll
          for (int r4 = 0; r4 < 4; ++r4) t4[r4] *= aa[r4];
          o[nf] = t4;
        }
        mrow = mn;
      }
      float p[8];
#pragma unroll
      for (int jq = 0; jq < 8; ++jq) p[jq] = __builtin_amdgcn_exp2f(sv[jq] - mrow);
      lrow += ((p[0] + p[1]) + (p[2] + p[3])) + ((p[4] + p[5]) + (p[6] + p[7]));
      asm volatile("" ::: "memory");
      Pw[lc * 20 + lg * 2 + 0] = cvtpk_bf16(p[0], p[1]);
      Pw[lc * 20 + lg * 2 + 1] = cvtpk_bf16(p[2], p[3]);
      Pw[lc * 20 + 8 + lg * 2 + 0] = cvtpk_bf16(p[4], p[5]);
      Pw[lc * 20 + 8 + lg * 2 + 1] = cvtpk_bf16(p[6], p[7]);
      asm volatile("" ::: "memory");
      short8 pf = *(const short8*)&Pm[lc * 40 + lg * 8];
      __builtin_amdgcn_s_setprio(1);
#pragma unroll
      for (int nf = 0; nf < 16; ++nf) {
        const int d = nf * 16 + lc;
        short8 vf = *(const short8*)(VsB + d * 64 + ((lg * 16) ^ (((d >> 1) & 3) << 4)));
        o[nf] = mfma16(pf, vf, o[nf]);
      }
      __builtin_amdgcn_s_setprio(0);
      asm volatile("" ::: "memory");
    }
    __syncthreads();
  }

  float lt = lrow + __shfl_xor(lrow, 16);
  lt += __shfl_xor(lt, 32);
  float il = 1.0f / lt;
  float ia[4];
#pragma unroll
  for (int r4 = 0; r4 < 4; ++r4) ia[r4] = __shfl(il, lg * 4 + r4);
  const int crow0 = (bh >> 4) * 2048 + qr;
  const int ccol0 = (bh & 15) * 256;
#pragma unroll
  for (int nf = 0; nf < 16; ++nf)
#pragma unroll
    for (int r4 = 0; r4 < 4; ++r4)
      ctx[(size_t)(crow0 + lg * 4 + r4) * 4096 + ccol0 + nf * 16 + lc] =
          f2bf(o[nf][r4] * ia[r4]);
}

// ---------- launcher ----------
extern "C" void kernel_launch(void* const* d_in, const int* in_sizes, int n_in,
                              void* d_out, int out_size, void* d_ws, size_t ws_size,
                              hipStream_t stream) {
  const float* hidden = (const float*)d_in[0];
  const float* Wq = (const float*)d_in[1];
  const float* Wk = (const float*)d_in[2];
  const float* Wv = (const float*)d_in[3];
  const float* Wo = (const float*)d_in[4];
  const int* pos = (const int*)d_in[5];

  const size_t NEL = 16777216;  // 4096*4096
  if (ws_size < 6 * NEL * sizeof(u16)) return;  // need 192 MB scratch

  u16* hb = (u16*)d_ws;      // hidden bf16; reused as ctx after QKV GEMMs
  u16* wq = hb + NEL;        // wq,wk,wv contiguous -> gemm_qkv indexes by tensor
  u16* wk = wq + NEL;
  u16* wv = wk + NEL;
  u16* wo = wv + NEL;
  u16* vt = wo + NEL;        // V^T [bh][d][s]
  u16* ctx = hb;
  u16* qb = (u16*)d_out;     // Q,K contiguous in d_out; overwritten by final GEMM
  u16* kb = qb + NEL;

  cvt_bf16_5<<<40960, 256, 0, stream>>>(hidden, Wq, Wk, Wv, Wo, hb);

  // Merged QKV GEMM (768 blocks). Q pre-scaled by log2(e)/16 (exp2-domain flash).
  gemm_qkv<<<768, 512, 0, stream>>>(hb, wq, qb, vt, 0.09016844f);

  rope_qk<<<16384, 256, 0, stream>>>(qb, kb, pos);

  flash_attn<<<512, 512, 0, stream>>>(qb, kb, vt, ctx);

  gemm_wo<<<256, 512, 0, stream>>>(ctx, wo, (float*)d_out);
}